// Round 4
// baseline (972.898 us; speedup 1.0000x reference)
//
#include <hip/hip_runtime.h>
#include <math.h>

// Problem constants
#define N_ROWS 32768      // B*H*W = 8*64*64
#define K_CODES 4096
#define D_DIM 256
#define HW 4096           // H*W
#define CHW 1048576       // C*H*W = 256*4096

// Output layout (float element offsets): loss(1) | quantized(8388608) | perplexity(1)
//                                        | encodings(32768*4096) | idx(32768)
#define OFF_LOSS  0
#define OFF_QUANT 1ULL
#define OFF_PERP  8388609ULL
#define OFF_ENC   8388610ULL
#define OFF_IDX   142606338ULL

// Workspace layout (float element offsets)
#define WS_RN   0           // 32768 row norms
#define WS_EN   32768       // 4096 code norms
#define WS_KEY  36864       // 32768 x u64 keys (d_bits<<32|code)
#define WS_CNT  102400      // 4096 uint counts
#define WS_LOSS 106496      // 1 double
#define WS_CCNT 106498      // (unused legacy slot)
#define WS_CNT2 106499      // candidate counter (u32)
#define WS_THR  106504      // 32768 per-row f32 final score min
#define WS_CAND 139272      // candidate list, CAP u32
#define CAP     1048576
#define WS_CBF  1187848     // codebook bf16 (1M shorts = 524288 floats); 16B aligned
#define WS_NEED_BYTES ((1187848ULL + 524288ULL) * 4ULL)   // ~6.85 MB (PROVEN to engage)

#define MARGIN 1.5e-3f      // worst-case |approx-exact| <= 2.8e-4 : 5x headroom
#define LBUF_N 2304         // per-block LDS pair buffer (expected ~1900 online hits)

typedef short bf16x8 __attribute__((ext_vector_type(8)));
typedef float f32x4 __attribute__((ext_vector_type(4)));

// fp32 -> bf16 RNE
__device__ __forceinline__ unsigned short f2bf(float f) {
  unsigned u = __float_as_uint(f);
  unsigned r = u + 0x7FFFu + ((u >> 16) & 1u);
  return (unsigned short)(r >> 16);
}

// async global->LDS, 16B per lane. LDS dest must be (wave-uniform base + lane*16).
__device__ __forceinline__ void async16(void* lds, const void* g) {
  typedef const __attribute__((address_space(1))) void* gvp;
  typedef __attribute__((address_space(3))) void* lvp;
  __builtin_amdgcn_global_load_lds((gvp)g, (lvp)lds, 16, 0, 0);
}

// numpy pairwise_sum replica for 128 squared elements (must stay bit-identical).
__device__ __forceinline__ float pairwise_sq_128(const float* __restrict__ p, int stride) {
  float r[8];
#pragma unroll
  for (int j = 0; j < 8; ++j) { float v = p[(size_t)j * stride]; r[j] = v * v; }
#pragma unroll
  for (int g = 1; g < 16; ++g) {
#pragma unroll
    for (int j = 0; j < 8; ++j) { float v = p[(size_t)(g * 8 + j) * stride]; r[j] += v * v; }
  }
  return ((r[0] + r[1]) + (r[2] + r[3])) + ((r[4] + r[5]) + (r[6] + r[7]));
}

__global__ void rownorm_k(const float* __restrict__ z, float* __restrict__ rn) {
  int row = blockIdx.x * 256 + threadIdx.x;
  const float* p = z + (size_t)(row >> 12) * CHW + (row & (HW - 1));
  rn[row] = pairwise_sq_128(p, HW) + pairwise_sq_128(p + (size_t)128 * HW, HW);
}

__global__ void enorm_k(const float* __restrict__ cb, float* __restrict__ en) {
  int k = blockIdx.x * 256 + threadIdx.x;
  const float* p = cb + (size_t)k * D_DIM;
  en[k] = pairwise_sq_128(p, 1) + pairwise_sq_128(p + 128, 1);
}

__global__ void cbbf_k(const float* __restrict__ cb, unsigned short* __restrict__ cbf) {
  int i = (blockIdx.x * 256 + threadIdx.x) * 4;
  float4 v = *(const float4*)(cb + i);
  unsigned d0 = f2bf(v.x) | ((unsigned)f2bf(v.y) << 16);
  unsigned d1 = f2bf(v.z) | ((unsigned)f2bf(v.w) << 16);
  *(int2*)(cbf + i) = make_int2((int)d0, (int)d1);
}

// Stage one 128-code x 64-dim bf16 B-tile (16 KB) into a double-buffer half,
// via 4 global_load_lds per thread. LDS layout is linear in chunk index i
// (dest = base + i*16B); the fragment swizzle is applied to the GLOBAL source
// address instead (m104/m173 pattern).
__device__ __forceinline__ void stageB(const unsigned short* __restrict__ cbf,
                                       short* bs, int tile, int ph2, int tid) {
#pragma unroll
  for (int k = 0; k < 4; ++k) {
    int i = tid + k * 256;
    int ks2 = i >> 9, s = i & 511;
    int ct = s >> 6, g = (s >> 4) & 3, m = s & 15;
    const unsigned short* src =
        cbf + (size_t)(tile * 128 + ct * 16 + m) * 256 + ph2 * 64 + ks2 * 32 + g * 8;
    async16(bs + (size_t)i * 8, src);
  }
}

// ============ SINGLE-PASS online filter, A-in-registers, 3 blocks/CU ============
// Block = 64 rows x ALL 4096 codes (32 tiles of 128). Per wave: its 16-row A-slab
// lives in 32 VGPRs (8x bf16x8), staged once through the (reused) B LDS buffer.
// B double-buffered in LDS, prefetched one phase ahead with global_load_lds; one
// barrier per 64-dim phase. Per tile: running row-min (incl. current tile), emit
// (pc, f32 score) into the LDS pair buffer when s <= running_rowmin + MARGIN
// (superset of the final-threshold set -> exact argmin always emitted). Block
// scans ALL codes of its rows, so it knows the FINAL rowmin at the end: re-cut
// the LDS pairs with the final threshold (bit-identical criterion to the proven
// second pass) and flush survivors via wave-aggregated compaction. LDS overflow
// spills raw pc to cand (conservative superset; verify_k absorbs).
// LDS: 32 KB (BS2) + 18 KB (lbuf) + 0.3 KB -> ~50.4 KB => 3 blocks/CU.
__global__ __launch_bounds__(256, 3) void pass5_k(
    const float* __restrict__ z, const unsigned short* __restrict__ cbf,
    const float* __restrict__ en, float* __restrict__ rowmin,
    unsigned int* __restrict__ cand, unsigned int* __restrict__ cnt2) {
  __shared__ __align__(16) short BS2[2 * 1024 * 8];     // 32 KB: A-stage, then B dbuf
  __shared__ unsigned int lbuf[2 * LBUF_N];             // 18 KB pairs (pc, score)
  __shared__ float rmf[64];                             // final per-row min
  __shared__ unsigned int lcnt;

  const int tid = threadIdx.x;
  const int lane = tid & 63;
  const int w = tid >> 6;                 // wave id = row-tile
  const int row_base = blockIdx.x * 64;
  const float* zb = z + (size_t)(row_base >> 12) * CHW + (row_base & (HW - 1));

  if (tid == 0) lcnt = 0;

  // ---- Stage A into BS2 (same swizzle as proven ASw layout) ----
  {
    int f4 = tid & 15;
    int r0 = f4 * 4;
#pragma unroll
    for (int it = 0; it < 2; ++it) {
      int c_oct = (tid >> 4) + it * 16;
      float4 v[8];
#pragma unroll
      for (int j = 0; j < 8; ++j)
        v[j] = *(const float4*)(zb + (size_t)(c_oct * 8 + j) * HW + r0);
      int s = c_oct >> 2, g = c_oct & 3;
#pragma unroll
      for (int i = 0; i < 4; ++i) {
        int r = r0 + i, rt = r >> 4, m = r & 15;
        int dw[4];
#pragma unroll
        for (int k = 0; k < 4; ++k) {
          unsigned lo = f2bf(((const float*)&v[2 * k])[i]);
          unsigned hi = f2bf(((const float*)&v[2 * k + 1])[i]);
          dw[k] = (int)(lo | (hi << 16));
        }
        *(int4*)&BS2[(((rt * 8 + s) * 64) + g * 16 + m) * 8] =
            make_int4(dw[0], dw[1], dw[2], dw[3]);
      }
    }
  }
  __syncthreads();

  // ---- Each wave pulls its 8 A-fragments (16 rows x 256 dims) into VGPRs ----
  bf16x8 aF[8];
#pragma unroll
  for (int s = 0; s < 8; ++s)
    aF[s] = *(const bf16x8*)&BS2[((w * 8 + s) * 64 + lane) * 8];
  __syncthreads();   // all waves done reading A before BS2 is reused for B

  unsigned rowenc[4];
#pragma unroll
  for (int r = 0; r < 4; ++r)
    rowenc[r] = (unsigned)(row_base + w * 16 + (lane >> 4) * 4 + r) << 12;

  float rmin[4] = {3.4e38f, 3.4e38f, 3.4e38f, 3.4e38f};

  stageB(cbf, BS2, 0, 0, tid);            // prologue prefetch into buf 0
  int pidx = 0;
  for (int tile = 0; tile < 32; ++tile) {
    float ev[8];
#pragma unroll
    for (int ct = 0; ct < 8; ++ct) ev[ct] = en[tile * 128 + ct * 16 + (lane & 15)];

    f32x4 acc[8];
#pragma unroll
    for (int ct = 0; ct < 8; ++ct) acc[ct] = (f32x4){0.f, 0.f, 0.f, 0.f};

#pragma unroll
    for (int ph2 = 0; ph2 < 4; ++ph2, ++pidx) {
      __syncthreads();   // drains my prefetch (implicit vmcnt(0)); buf^1 free
      int nx = pidx + 1;
      if (nx < 128) stageB(cbf, BS2 + (nx & 1) * 8192, nx >> 2, nx & 3, tid);

      const short* bb = BS2 + (pidx & 1) * 8192;
      bf16x8 a0 = aF[ph2 * 2 + 0];
      bf16x8 a1 = aF[ph2 * 2 + 1];
      __builtin_amdgcn_s_setprio(1);
#pragma unroll
      for (int ct = 0; ct < 8; ++ct) {
        bf16x8 b0 = *(const bf16x8*)&bb[(ct * 64 + lane) * 8];
        acc[ct] = __builtin_amdgcn_mfma_f32_16x16x32_bf16(a0, b0, acc[ct], 0, 0, 0);
      }
#pragma unroll
      for (int ct = 0; ct < 8; ++ct) {
        bf16x8 b1 = *(const bf16x8*)&bb[(512 + ct * 64 + lane) * 8];
        acc[ct] = __builtin_amdgcn_mfma_f32_16x16x32_bf16(a1, b1, acc[ct], 0, 0, 0);
      }
      __builtin_amdgcn_s_setprio(0);
    }

    // ---- tile epilogue: running min (incl. this tile) -> threshold -> emit ----
#pragma unroll
    for (int ct = 0; ct < 8; ++ct)
#pragma unroll
      for (int r = 0; r < 4; ++r)
        rmin[r] = fminf(rmin[r], ev[ct] - 2.0f * acc[ct][r]);

    float thr2[4];
#pragma unroll
    for (int r = 0; r < 4; ++r) {
      float v = rmin[r];
      v = fminf(v, __shfl_xor(v, 1));
      v = fminf(v, __shfl_xor(v, 2));
      v = fminf(v, __shfl_xor(v, 4));
      v = fminf(v, __shfl_xor(v, 8));
      thr2[r] = v + MARGIN;
    }

#pragma unroll
    for (int ct = 0; ct < 8; ++ct) {
      unsigned code = (unsigned)(tile * 128 + ct * 16 + (lane & 15));
#pragma unroll
      for (int r = 0; r < 4; ++r) {
        float s = ev[ct] - 2.0f * acc[ct][r];
        if (s <= thr2[r]) {
          unsigned pc = rowenc[r] | code;
          unsigned pos = atomicAdd(&lcnt, 1u);
          if (pos < LBUF_N) {
            lbuf[2 * pos] = pc;
            lbuf[2 * pos + 1] = __float_as_uint(s);
          } else {
            // rare spill: conservative (skips final re-cut); verify absorbs
            unsigned g = atomicAdd(cnt2, 1u);
            if (g < CAP) cand[g] = pc;
          }
        }
      }
    }
  }

  // Final per-row min -> global rowmin + LDS rmf (block owns its rows).
#pragma unroll
  for (int r = 0; r < 4; ++r) {
    float v = rmin[r];
    v = fminf(v, __shfl_xor(v, 1));
    v = fminf(v, __shfl_xor(v, 2));
    v = fminf(v, __shfl_xor(v, 4));
    v = fminf(v, __shfl_xor(v, 8));
    if ((lane & 15) == 0) {
      unsigned row = rowenc[r] >> 12;
      rowmin[row] = v;
      rmf[row & 63] = v;
    }
  }

  // Re-cut LDS pairs against the FINAL threshold; wave-aggregated compaction.
  __syncthreads();
  unsigned n = lcnt; if (n > LBUF_N) n = LBUF_N;
  for (unsigned i0 = 0; i0 < n; i0 += 256) {
    unsigned i = i0 + tid;
    bool keep = false; unsigned pc = 0;
    if (i < n) {
      pc = lbuf[2 * i];
      float s = __uint_as_float(lbuf[2 * i + 1]);
      keep = (s <= rmf[(pc >> 12) & 63] + MARGIN);   // == proven pass-2 criterion
    }
    unsigned long long m = __ballot(keep);
    unsigned wb = 0;
    if ((tid & 63) == 0 && m) wb = atomicAdd(cnt2, (unsigned)__popcll(m));
    wb = __shfl(wb, 0);
    if (keep) {
      unsigned off = (unsigned)__popcll(m & ((1ull << (tid & 63)) - 1ull));
      unsigned g = wb + off;
      if (g < CAP) cand[g] = pc;
    }
  }
}

// Exact re-verify: replay the exact fp32 fmaf chain (bit-identical to fallback).
__global__ void verify_k(const float* __restrict__ z, const float* __restrict__ cb,
                         const float* __restrict__ rn, const float* __restrict__ en,
                         const unsigned int* __restrict__ cand,
                         const unsigned int* __restrict__ cnt,
                         unsigned long long* __restrict__ key) {
  unsigned total = *cnt; if (total > CAP) total = CAP;
  for (unsigned i = blockIdx.x * 256 + threadIdx.x; i < total; i += gridDim.x * 256) {
    unsigned pc = cand[i];
    unsigned row = pc >> 12, code = pc & 4095u;
    const float* x = z + (size_t)(row >> 12) * CHW + (row & (HW - 1));
    const float* e = cb + (size_t)code * D_DIM;
    float acc = 0.0f;
#pragma unroll 8
    for (int c = 0; c < D_DIM; ++c) acc = fmaf(x[(size_t)c * HW], e[c], acc);
    float d = (rn[row] + en[code]) - 2.0f * acc;   // reference rounding order
    unsigned long long k64 = ((unsigned long long)__float_as_uint(d) << 32) | code;
    atomicMin(&key[row], k64);
  }
}

// ---------- fp32 argmin (small-ws fallback AND guarded backstop) ----------
// guard != nullptr: early-exit unless the candidate counter overflowed CAP
// (i.e., candidates may have been dropped) -> recompute everything exactly.
#define BM 128
#define BN 128
#define BK 32
#define KQ 1024
#define ES_S 36
__global__ __launch_bounds__(256, 3) void argmin_fb(
    const float* __restrict__ z, const float* __restrict__ cb,
    const float* __restrict__ rn, const float* __restrict__ en,
    unsigned long long* __restrict__ key, const unsigned int* __restrict__ guard) {
  if (guard && *guard <= CAP) return;
  __shared__ union {
    struct { float Xs[BK * BM]; float Es[BN * ES_S]; } s;
    struct { float rv[BM * 16]; int ri[BM * 16]; } r;
  } sh;
  const int tid = threadIdx.x;
  const int tx = tid & 15, ty = tid >> 4;
  const int row_base = (blockIdx.x >> 2) * BM;
  const int q = blockIdx.x & 3;
  const float* zb = z + (size_t)(row_base >> 12) * CHW + (row_base & (HW - 1));
  float rnv[8];
#pragma unroll
  for (int i = 0; i < 8; ++i) rnv[i] = rn[row_base + ty * 8 + i];
  float bestV[8]; int bestI[8];
#pragma unroll
  for (int i = 0; i < 8; ++i) { bestV[i] = 3.4e38f; bestI[i] = 0; }
  for (int t0 = q * KQ; t0 < q * KQ + KQ; t0 += BN) {
    float acc[8][8];
#pragma unroll
    for (int i = 0; i < 8; ++i)
#pragma unroll
      for (int j = 0; j < 8; ++j) acc[i][j] = 0.0f;
    for (int kb = 0; kb < D_DIM; kb += BK) {
      __syncthreads();
#pragma unroll
      for (int k = 0; k < 4; ++k) {
        int l4 = tid + k * 256, cl = l4 >> 5, ro = (l4 & 31) << 2;
        *(float4*)&sh.s.Xs[cl * BM + ro] = *(const float4*)(zb + (size_t)(kb + cl) * HW + ro);
      }
#pragma unroll
      for (int k = 0; k < 4; ++k) {
        int l4 = tid + k * 256, kl = l4 >> 3, cq = (l4 & 7) << 2;
        *(float4*)&sh.s.Es[kl * ES_S + cq] =
            *(const float4*)(cb + (size_t)(t0 + kl) * D_DIM + kb + cq);
      }
      __syncthreads();
#pragma unroll
      for (int c4 = 0; c4 < BK / 4; ++c4) {
        float4 ef[8];
#pragma unroll
        for (int j = 0; j < 8; ++j)
          ef[j] = *(const float4*)&sh.s.Es[(tx + 16 * j) * ES_S + c4 * 4];
#pragma unroll
        for (int cc = 0; cc < 4; ++cc) {
          int c = c4 * 4 + cc;
          float4 xa = *(const float4*)&sh.s.Xs[c * BM + ty * 8];
          float4 xb = *(const float4*)&sh.s.Xs[c * BM + ty * 8 + 4];
          float xv[8] = {xa.x, xa.y, xa.z, xa.w, xb.x, xb.y, xb.z, xb.w};
          float evv[8] = {((const float*)&ef[0])[cc], ((const float*)&ef[1])[cc],
                          ((const float*)&ef[2])[cc], ((const float*)&ef[3])[cc],
                          ((const float*)&ef[4])[cc], ((const float*)&ef[5])[cc],
                          ((const float*)&ef[6])[cc], ((const float*)&ef[7])[cc]};
#pragma unroll
          for (int i = 0; i < 8; ++i)
#pragma unroll
            for (int j = 0; j < 8; ++j) acc[i][j] = fmaf(xv[i], evv[j], acc[i][j]);
        }
      }
    }
#pragma unroll
    for (int j = 0; j < 8; ++j) {
      int code = t0 + tx + 16 * j;
      float ev = en[code];
#pragma unroll
      for (int i = 0; i < 8; ++i) {
        float d = (rnv[i] + ev) - 2.0f * acc[i][j];
        if (d < bestV[i]) { bestV[i] = d; bestI[i] = code; }
      }
    }
  }
  __syncthreads();
#pragma unroll
  for (int i = 0; i < 8; ++i) {
    sh.r.rv[(ty * 8 + i) * 16 + tx] = bestV[i];
    sh.r.ri[(ty * 8 + i) * 16 + tx] = bestI[i];
  }
  __syncthreads();
  if (tid < BM) {
    float bv = sh.r.rv[tid * 16]; int bi = sh.r.ri[tid * 16];
    for (int t = 1; t < 16; ++t) {
      float v = sh.r.rv[tid * 16 + t]; int ii = sh.r.ri[tid * 16 + t];
      if (v < bv || (v == bv && ii < bi)) { bv = v; bi = ii; }
    }
    unsigned long long k64 = ((unsigned long long)__float_as_uint(bv) << 32) | (unsigned)bi;
    atomicMin(&key[row_base + tid], k64);
  }
}
// ---------- end fallback ----------

__global__ void scatter_k(const unsigned long long* __restrict__ key,
                          unsigned int* __restrict__ counts, float* __restrict__ out) {
  int row = blockIdx.x * 256 + threadIdx.x;
  int bi = (int)(unsigned int)(key[row] & 0xffffffffULL);
  out[OFF_IDX + row] = (float)bi;
  out[OFF_ENC + (size_t)row * K_CODES + bi] = 1.0f;
  atomicAdd(&counts[bi], 1u);
}

__global__ void quant_k(const float* __restrict__ z, const float* __restrict__ cb,
                        const unsigned long long* __restrict__ key, float* __restrict__ out,
                        double* __restrict__ losssum) {
  __shared__ double red[256];
  int bh = blockIdx.x, b = bh >> 6, h = bh & 63;
  int tid = threadIdx.x, w = tid & 63, c0 = tid >> 6;
  int n = (b << 12) + (h << 6) + w;
  int iv = (int)(unsigned int)(key[n] & 0xffffffffULL);
  const float* cbr = cb + (size_t)iv * D_DIM;
  size_t zoff = (size_t)b * CHW + (size_t)(h << 6) + w;
  double s = 0.0;
  for (int c = c0; c < D_DIM; c += 4) {
    float zv = z[zoff + (size_t)c * HW];
    float qv = cbr[c];
    float diff = qv - zv;
    out[OFF_QUANT + zoff + (size_t)c * HW] = zv + diff;   // STE forward rounding
    double dd = (double)qv - (double)zv;
    s += dd * dd;
  }
  red[tid] = s;
  __syncthreads();
  for (int st = 128; st > 0; st >>= 1) {
    if (tid < st) red[tid] += red[tid + st];
    __syncthreads();
  }
  if (tid == 0) atomicAdd(losssum, red[0]);
}

__global__ void final_k(const unsigned int* __restrict__ counts,
                        const double* __restrict__ losssum, float* __restrict__ out) {
  __shared__ double red[256];
  int tid = threadIdx.x;
  double s = 0.0;
  for (int k = tid; k < K_CODES; k += 256) {
    double p = (double)counts[k] / 32768.0;
    s += p * log(p + 1e-10);
  }
  red[tid] = s;
  __syncthreads();
  for (int st = 128; st > 0; st >>= 1) {
    if (tid < st) red[tid] += red[tid + st];
    __syncthreads();
  }
  if (tid == 0) {
    out[OFF_PERP] = (float)exp(-red[0]);
    out[OFF_LOSS] = (float)(1.25 * losssum[0] / 8388608.0);
  }
}

extern "C" void kernel_launch(void* const* d_in, const int* in_sizes, int n_in,
                              void* d_out, int out_size, void* d_ws, size_t ws_size,
                              hipStream_t stream) {
  (void)in_sizes; (void)n_in; (void)out_size;
  const float* z = (const float*)d_in[0];
  const float* cb = (const float*)d_in[1];
  float* out = (float*)d_out;
  float* ws = (float*)d_ws;

  float* rn = ws + WS_RN;
  float* en = ws + WS_EN;
  unsigned long long* key = (unsigned long long*)(ws + WS_KEY);
  unsigned int* counts = (unsigned int*)(ws + WS_CNT);
  double* losssum = (double*)(ws + WS_LOSS);

  hipMemsetAsync(out + OFF_ENC, 0, (size_t)N_ROWS * K_CODES * sizeof(float), stream);
  hipMemsetAsync(ws + WS_KEY, 0xFF, (size_t)N_ROWS * sizeof(unsigned long long), stream);

  rownorm_k<<<N_ROWS / 256, 256, 0, stream>>>(z, rn);
  enorm_k<<<K_CODES / 256, 256, 0, stream>>>(cb, en);

  if (ws_size >= WS_NEED_BYTES) {
    unsigned int* cnt2 = (unsigned int*)(ws + WS_CNT2);
    float* rowmin = ws + WS_THR;
    unsigned int* cand = (unsigned int*)(ws + WS_CAND);
    unsigned short* cbf = (unsigned short*)(ws + WS_CBF);
    // zero counts(4096) + loss(2) + counters + pad
    hipMemsetAsync(ws + WS_CNT, 0, (WS_THR - WS_CNT) * sizeof(float), stream);
    cbbf_k<<<(K_CODES * D_DIM / 4) / 256, 256, 0, stream>>>(cb, cbf);
    // SINGLE MFMA pass: A-in-regs, 3 blocks/CU, online emission + in-block re-cut.
    pass5_k<<<N_ROWS / 64, 256, 0, stream>>>(z, cbf, en, rowmin, cand, cnt2);
    verify_k<<<1024, 256, 0, stream>>>(z, cb, rn, en, cand, cnt2, key);
    // Guarded backstop: full exact recompute ONLY if the candidate list
    // overflowed (entries possibly dropped). Normally ~5 us of early-exit.
    argmin_fb<<<(N_ROWS / BM) * 4, 256, 0, stream>>>(z, cb, rn, en, key, cnt2);
  } else {
    hipMemsetAsync(ws + WS_CNT, 0, K_CODES * sizeof(unsigned int) + 2 * sizeof(double), stream);
    argmin_fb<<<(N_ROWS / BM) * 4, 256, 0, stream>>>(z, cb, rn, en, key, nullptr);
  }

  scatter_k<<<N_ROWS / 256, 256, 0, stream>>>(key, counts, out);
  quant_k<<<512, 256, 0, stream>>>(z, cb, key, out, losssum);
  final_k<<<1, 256, 0, stream>>>(counts, losssum, out);
}

// Round 6
// 939.118 us; speedup vs baseline: 1.0360x; 1.0360x over previous
//
#include <hip/hip_runtime.h>
#include <math.h>

// Problem constants
#define N_ROWS 32768      // B*H*W = 8*64*64
#define K_CODES 4096
#define D_DIM 256
#define HW 4096           // H*W
#define CHW 1048576       // C*H*W = 256*4096

// Output layout (float element offsets): loss(1) | quantized(8388608) | perplexity(1)
//                                        | encodings(32768*4096) | idx(32768)
#define OFF_LOSS  0
#define OFF_QUANT 1ULL
#define OFF_PERP  8388609ULL
#define OFF_ENC   8388610ULL
#define OFF_IDX   142606338ULL

// Workspace layout (float element offsets)
#define WS_RN   0           // 32768 row norms
#define WS_EN   32768       // 4096 code norms
#define WS_KEY  36864       // 32768 x u64 keys (d_bits<<32|code)
#define WS_CNT  102400      // 4096 uint counts
#define WS_LOSS 106496      // 1 double
#define WS_CCNT 106498      // (unused legacy slot)
#define WS_CNT2 106499      // candidate counter (u32)
#define WS_THR  106504      // 32768 per-row f32 final score min
#define WS_CAND 139272      // candidate list, CAP u32
#define CAP     1048576
#define WS_CBF  1187848     // codebook bf16 (1M shorts = 524288 floats); 16B aligned
#define WS_NEED_BYTES ((1187848ULL + 524288ULL) * 4ULL)   // ~6.85 MB (PROVEN to engage)

#define MARGIN 1.5e-3f      // worst-case |approx-exact| <= 2.8e-4 : 5x headroom
#define LBUF_N 1536         // per-block LDS pair buffer

typedef short bf16x8 __attribute__((ext_vector_type(8)));
typedef float f32x4 __attribute__((ext_vector_type(4)));

// fp32 -> bf16 RNE
__device__ __forceinline__ unsigned short f2bf(float f) {
  unsigned u = __float_as_uint(f);
  unsigned r = u + 0x7FFFu + ((u >> 16) & 1u);
  return (unsigned short)(r >> 16);
}

// async global->LDS, 16B per lane. LDS dest must be (wave-uniform base + lane*16).
__device__ __forceinline__ void async16(void* lds, const void* g) {
  typedef const __attribute__((address_space(1))) void* gvp;
  typedef __attribute__((address_space(3))) void* lvp;
  __builtin_amdgcn_global_load_lds((gvp)g, (lvp)lds, 16, 0, 0);
}

// numpy pairwise_sum replica for 128 squared elements (must stay bit-identical).
__device__ __forceinline__ float pairwise_sq_128(const float* __restrict__ p, int stride) {
  float r[8];
#pragma unroll
  for (int j = 0; j < 8; ++j) { float v = p[(size_t)j * stride]; r[j] = v * v; }
#pragma unroll
  for (int g = 1; g < 16; ++g) {
#pragma unroll
    for (int j = 0; j < 8; ++j) { float v = p[(size_t)(g * 8 + j) * stride]; r[j] += v * v; }
  }
  return ((r[0] + r[1]) + (r[2] + r[3])) + ((r[4] + r[5]) + (r[6] + r[7]));
}

__global__ void rownorm_k(const float* __restrict__ z, float* __restrict__ rn) {
  int row = blockIdx.x * 256 + threadIdx.x;
  const float* p = z + (size_t)(row >> 12) * CHW + (row & (HW - 1));
  rn[row] = pairwise_sq_128(p, HW) + pairwise_sq_128(p + (size_t)128 * HW, HW);
}

__global__ void enorm_k(const float* __restrict__ cb, float* __restrict__ en) {
  int k = blockIdx.x * 256 + threadIdx.x;
  const float* p = cb + (size_t)k * D_DIM;
  en[k] = pairwise_sq_128(p, 1) + pairwise_sq_128(p + 128, 1);
}

__global__ void cbbf_k(const float* __restrict__ cb, unsigned short* __restrict__ cbf) {
  int i = (blockIdx.x * 256 + threadIdx.x) * 4;
  float4 v = *(const float4*)(cb + i);
  unsigned d0 = f2bf(v.x) | ((unsigned)f2bf(v.y) << 16);
  unsigned d1 = f2bf(v.z) | ((unsigned)f2bf(v.w) << 16);
  *(int2*)(cbf + i) = make_int2((int)d0, (int)d1);
}

// Stage one 128-code x 64-dim bf16 B-tile (16 KB) into a double-buffer half,
// via 4 global_load_lds per thread. LDS layout is linear in chunk index i
// (dest = base + i*16B); the fragment swizzle is applied to the GLOBAL source
// address instead (m104/m173 pattern).
__device__ __forceinline__ void stageB(const unsigned short* __restrict__ cbf,
                                       short* bs, int tile, int ph2, int tid) {
#pragma unroll
  for (int k = 0; k < 4; ++k) {
    int i = tid + k * 256;
    int ks2 = i >> 9, s = i & 511;
    int ct = s >> 6, g = (s >> 4) & 3, m = s & 15;
    const unsigned short* src =
        cbf + (size_t)(tile * 128 + ct * 16 + m) * 256 + ph2 * 64 + ks2 * 32 + g * 8;
    async16(bs + (size_t)i * 8, src);
  }
}

// ============ SINGLE-PASS online filter (r3 structure + fused exact rownorm) ============
// Block = 64 rows x ALL 4096 codes (32 tiles of 128). Pipelined B double-buffer,
// one barrier per 64-dim phase. During A-staging the fp32 z values are also
// squared into a 32 KB LDS scratch (reusing the not-yet-active B buffer) and
// 64 reducer threads replay numpy's pairwise tree BIT-EXACTLY (sequential
// g=0..15 per 8-lane accumulator, same fold, halves added last) -> rn[].
// This deletes the separate rownorm kernel's 128 MB z re-read.
// Per tile: running row-min (incl. current tile), emit (pc, f32 score) into the
// LDS pair buffer when s <= running_rowmin + MARGIN (superset of the final-
// threshold set -> exact argmin always emitted). Block scans ALL codes of its
// rows, so it knows the FINAL rowmin at the end: re-cut the LDS pairs with the
// final threshold (bit-identical criterion to the proven second pass) and flush
// survivors via wave-aggregated compaction. LDS overflow spills raw pc to cand
// (conservative superset; verify_k absorbs).
__global__ __launch_bounds__(256, 2) void pass4f_k(
    const float* __restrict__ z, const unsigned short* __restrict__ cbf,
    const float* __restrict__ en, float* __restrict__ rn,
    float* __restrict__ rowmin,
    unsigned int* __restrict__ cand, unsigned int* __restrict__ cnt2) {
  __shared__ __align__(16) short ASw[4 * 8 * 64 * 8];   // 32 KB
  __shared__ __align__(16) short BS2[2 * 1024 * 8];     // 32 KB (scratch during A-stage)
  __shared__ unsigned int lbuf[2 * LBUF_N];             // 12 KB pairs (pc, score)
  __shared__ float rmf[64];                             // rn half-0 temp, later final row min
  __shared__ unsigned int lcnt;

  const int tid = threadIdx.x;
  const int lane = tid & 63;
  const int w = tid >> 6;                 // wave id = row-tile
  const int row_base = blockIdx.x * 64;
  const float* zb = z + (size_t)(row_base >> 12) * CHW + (row_base & (HW - 1));

  if (tid == 0) lcnt = 0;

  // ---- Stage A: 64 rows x 256 dims, fp32->bf16, swizzled to A-frag order,
  //      plus exact-square partials for the fused rownorm ----
  {
    float* pf = (float*)BS2;              // 16 g-groups x 64 rows x 8 lanes = 32 KB
    int f4 = tid & 15;
    int r0 = f4 * 4;
    int g16 = tid >> 4;                   // pairwise g-group (per half)
#pragma unroll
    for (int it = 0; it < 2; ++it) {
      int c_oct = (tid >> 4) + it * 16;   // 8-dim octet 0..31
      float4 v[8];
#pragma unroll
      for (int j = 0; j < 8; ++j)
        v[j] = *(const float4*)(zb + (size_t)(c_oct * 8 + j) * HW + r0);
      int s = c_oct >> 2, g = c_oct & 3;
#pragma unroll
      for (int i = 0; i < 4; ++i) {
        int r = r0 + i, rt = r >> 4, m = r & 15;
        int dw[4];
#pragma unroll
        for (int k = 0; k < 4; ++k) {
          unsigned lo = f2bf(((const float*)&v[2 * k])[i]);
          unsigned hi = f2bf(((const float*)&v[2 * k + 1])[i]);
          dw[k] = (int)(lo | (hi << 16));
        }
        *(int4*)&ASw[(((rt * 8 + s) * 64) + g * 16 + m) * 8] =
            make_int4(dw[0], dw[1], dw[2], dw[3]);
        // exact squares (fp32, element-wise identical to rownorm_k's v*v)
#pragma unroll
        for (int j = 0; j < 8; ++j) {
          float x = ((const float*)&v[j])[i];
          pf[(g16 * 64 + r) * 8 + j] = x * x;
        }
      }
      __syncthreads();
      // 64 reducers: numpy pairwise tree, bit-exact (sequential g, same fold)
      if (tid < 64) {
        float racc[8];
#pragma unroll
        for (int j = 0; j < 8; ++j) racc[j] = pf[(size_t)tid * 8 + j];
        for (int gg = 1; gg < 16; ++gg)
#pragma unroll
          for (int j = 0; j < 8; ++j) racc[j] += pf[(gg * 64 + tid) * 8 + j];
        float h = ((racc[0] + racc[1]) + (racc[2] + racc[3])) +
                  ((racc[4] + racc[5]) + (racc[6] + racc[7]));
        if (it == 0) rmf[tid] = h;                      // first 128-dim half
        else rn[row_base + tid] = rmf[tid] + h;         // + second half (ref order)
      }
      __syncthreads();
    }
  }

  unsigned rowenc[4];
#pragma unroll
  for (int r = 0; r < 4; ++r)
    rowenc[r] = (unsigned)(row_base + w * 16 + (lane >> 4) * 4 + r) << 12;

  float rmin[4] = {3.4e38f, 3.4e38f, 3.4e38f, 3.4e38f};

  stageB(cbf, BS2, 0, 0, tid);            // prologue prefetch into buf 0
  int pidx = 0;
  for (int tile = 0; tile < 32; ++tile) {
    float ev[8];
#pragma unroll
    for (int ct = 0; ct < 8; ++ct) ev[ct] = en[tile * 128 + ct * 16 + (lane & 15)];

    f32x4 acc[8];
#pragma unroll
    for (int ct = 0; ct < 8; ++ct) acc[ct] = (f32x4){0.f, 0.f, 0.f, 0.f};

#pragma unroll
    for (int ph2 = 0; ph2 < 4; ++ph2, ++pidx) {
      __syncthreads();   // drains my prefetch (implicit vmcnt(0)); buf^1 free
      int nx = pidx + 1;
      if (nx < 128) stageB(cbf, BS2 + (nx & 1) * 8192, nx >> 2, nx & 3, tid);

      const short* bb = BS2 + (pidx & 1) * 8192;
      bf16x8 a0 = *(const bf16x8*)&ASw[((w * 8 + ph2 * 2 + 0) * 64 + lane) * 8];
      bf16x8 a1 = *(const bf16x8*)&ASw[((w * 8 + ph2 * 2 + 1) * 64 + lane) * 8];
      __builtin_amdgcn_s_setprio(1);
#pragma unroll
      for (int ct = 0; ct < 8; ++ct) {
        bf16x8 b0 = *(const bf16x8*)&bb[(ct * 64 + lane) * 8];
        acc[ct] = __builtin_amdgcn_mfma_f32_16x16x32_bf16(a0, b0, acc[ct], 0, 0, 0);
      }
#pragma unroll
      for (int ct = 0; ct < 8; ++ct) {
        bf16x8 b1 = *(const bf16x8*)&bb[(512 + ct * 64 + lane) * 8];
        acc[ct] = __builtin_amdgcn_mfma_f32_16x16x32_bf16(a1, b1, acc[ct], 0, 0, 0);
      }
      __builtin_amdgcn_s_setprio(0);
    }

    // ---- tile epilogue: running min (incl. this tile) -> threshold -> emit ----
#pragma unroll
    for (int ct = 0; ct < 8; ++ct)
#pragma unroll
      for (int r = 0; r < 4; ++r)
        rmin[r] = fminf(rmin[r], ev[ct] - 2.0f * acc[ct][r]);

    float thr2[4];
#pragma unroll
    for (int r = 0; r < 4; ++r) {
      float v = rmin[r];
      v = fminf(v, __shfl_xor(v, 1));
      v = fminf(v, __shfl_xor(v, 2));
      v = fminf(v, __shfl_xor(v, 4));
      v = fminf(v, __shfl_xor(v, 8));
      thr2[r] = v + MARGIN;
    }

#pragma unroll
    for (int ct = 0; ct < 8; ++ct) {
      unsigned code = (unsigned)(tile * 128 + ct * 16 + (lane & 15));
#pragma unroll
      for (int r = 0; r < 4; ++r) {
        float s = ev[ct] - 2.0f * acc[ct][r];
        if (s <= thr2[r]) {
          unsigned pc = rowenc[r] | code;
          unsigned pos = atomicAdd(&lcnt, 1u);
          if (pos < LBUF_N) {
            lbuf[2 * pos] = pc;
            lbuf[2 * pos + 1] = __float_as_uint(s);
          } else {
            // rare spill: conservative (skips final re-cut); verify absorbs
            unsigned g = atomicAdd(cnt2, 1u);
            if (g < CAP) cand[g] = pc;
          }
        }
      }
    }
  }

  // Final per-row min -> global rowmin + LDS rmf (block owns its rows).
#pragma unroll
  for (int r = 0; r < 4; ++r) {
    float v = rmin[r];
    v = fminf(v, __shfl_xor(v, 1));
    v = fminf(v, __shfl_xor(v, 2));
    v = fminf(v, __shfl_xor(v, 4));
    v = fminf(v, __shfl_xor(v, 8));
    if ((lane & 15) == 0) {
      unsigned row = rowenc[r] >> 12;
      rowmin[row] = v;
      rmf[row & 63] = v;
    }
  }

  // Re-cut LDS pairs against the FINAL threshold; wave-aggregated compaction.
  __syncthreads();
  unsigned n = lcnt; if (n > LBUF_N) n = LBUF_N;
  for (unsigned i0 = 0; i0 < n; i0 += 256) {
    unsigned i = i0 + tid;
    bool keep = false; unsigned pc = 0;
    if (i < n) {
      pc = lbuf[2 * i];
      float s = __uint_as_float(lbuf[2 * i + 1]);
      keep = (s <= rmf[(pc >> 12) & 63] + MARGIN);   // == proven pass-2 criterion
    }
    unsigned long long m = __ballot(keep);
    unsigned wb = 0;
    if ((tid & 63) == 0 && m) wb = atomicAdd(cnt2, (unsigned)__popcll(m));
    wb = __shfl(wb, 0);
    if (keep) {
      unsigned off = (unsigned)__popcll(m & ((1ull << (tid & 63)) - 1ull));
      unsigned g = wb + off;
      if (g < CAP) cand[g] = pc;
    }
  }
}

// Exact re-verify: replay the exact fp32 fmaf chain (bit-identical to fallback).
__global__ void verify_k(const float* __restrict__ z, const float* __restrict__ cb,
                         const float* __restrict__ rn, const float* __restrict__ en,
                         const unsigned int* __restrict__ cand,
                         const unsigned int* __restrict__ cnt,
                         unsigned long long* __restrict__ key) {
  unsigned total = *cnt; if (total > CAP) total = CAP;
  for (unsigned i = blockIdx.x * 256 + threadIdx.x; i < total; i += gridDim.x * 256) {
    unsigned pc = cand[i];
    unsigned row = pc >> 12, code = pc & 4095u;
    const float* x = z + (size_t)(row >> 12) * CHW + (row & (HW - 1));
    const float* e = cb + (size_t)code * D_DIM;
    float acc = 0.0f;
#pragma unroll 8
    for (int c = 0; c < D_DIM; ++c) acc = fmaf(x[(size_t)c * HW], e[c], acc);
    float d = (rn[row] + en[code]) - 2.0f * acc;   // reference rounding order
    unsigned long long k64 = ((unsigned long long)__float_as_uint(d) << 32) | code;
    atomicMin(&key[row], k64);
  }
}

// ---------- fp32 argmin (small-ws fallback AND guarded backstop) ----------
// guard != nullptr: early-exit unless the candidate counter overflowed CAP
// (i.e., candidates may have been dropped) -> recompute everything exactly.
#define BM 128
#define BN 128
#define BK 32
#define KQ 1024
#define ES_S 36
__global__ __launch_bounds__(256, 3) void argmin_fb(
    const float* __restrict__ z, const float* __restrict__ cb,
    const float* __restrict__ rn, const float* __restrict__ en,
    unsigned long long* __restrict__ key, const unsigned int* __restrict__ guard) {
  if (guard && *guard <= CAP) return;
  __shared__ union {
    struct { float Xs[BK * BM]; float Es[BN * ES_S]; } s;
    struct { float rv[BM * 16]; int ri[BM * 16]; } r;
  } sh;
  const int tid = threadIdx.x;
  const int tx = tid & 15, ty = tid >> 4;
  const int row_base = (blockIdx.x >> 2) * BM;
  const int q = blockIdx.x & 3;
  const float* zb = z + (size_t)(row_base >> 12) * CHW + (row_base & (HW - 1));
  float rnv[8];
#pragma unroll
  for (int i = 0; i < 8; ++i) rnv[i] = rn[row_base + ty * 8 + i];
  float bestV[8]; int bestI[8];
#pragma unroll
  for (int i = 0; i < 8; ++i) { bestV[i] = 3.4e38f; bestI[i] = 0; }
  for (int t0 = q * KQ; t0 < q * KQ + KQ; t0 += BN) {
    float acc[8][8];
#pragma unroll
    for (int i = 0; i < 8; ++i)
#pragma unroll
      for (int j = 0; j < 8; ++j) acc[i][j] = 0.0f;
    for (int kb = 0; kb < D_DIM; kb += BK) {
      __syncthreads();
#pragma unroll
      for (int k = 0; k < 4; ++k) {
        int l4 = tid + k * 256, cl = l4 >> 5, ro = (l4 & 31) << 2;
        *(float4*)&sh.s.Xs[cl * BM + ro] = *(const float4*)(zb + (size_t)(kb + cl) * HW + ro);
      }
#pragma unroll
      for (int k = 0; k < 4; ++k) {
        int l4 = tid + k * 256, kl = l4 >> 3, cq = (l4 & 7) << 2;
        *(float4*)&sh.s.Es[kl * ES_S + cq] =
            *(const float4*)(cb + (size_t)(t0 + kl) * D_DIM + kb + cq);
      }
      __syncthreads();
#pragma unroll
      for (int c4 = 0; c4 < BK / 4; ++c4) {
        float4 ef[8];
#pragma unroll
        for (int j = 0; j < 8; ++j)
          ef[j] = *(const float4*)&sh.s.Es[(tx + 16 * j) * ES_S + c4 * 4];
#pragma unroll
        for (int cc = 0; cc < 4; ++cc) {
          int c = c4 * 4 + cc;
          float4 xa = *(const float4*)&sh.s.Xs[c * BM + ty * 8];
          float4 xb = *(const float4*)&sh.s.Xs[c * BM + ty * 8 + 4];
          float xv[8] = {xa.x, xa.y, xa.z, xa.w, xb.x, xb.y, xb.z, xb.w};
          float evv[8] = {((const float*)&ef[0])[cc], ((const float*)&ef[1])[cc],
                          ((const float*)&ef[2])[cc], ((const float*)&ef[3])[cc],
                          ((const float*)&ef[4])[cc], ((const float*)&ef[5])[cc],
                          ((const float*)&ef[6])[cc], ((const float*)&ef[7])[cc]};
#pragma unroll
          for (int i = 0; i < 8; ++i)
#pragma unroll
            for (int j = 0; j < 8; ++j) acc[i][j] = fmaf(xv[i], evv[j], acc[i][j]);
        }
      }
    }
#pragma unroll
    for (int j = 0; j < 8; ++j) {
      int code = t0 + tx + 16 * j;
      float ev = en[code];
#pragma unroll
      for (int i = 0; i < 8; ++i) {
        float d = (rnv[i] + ev) - 2.0f * acc[i][j];
        if (d < bestV[i]) { bestV[i] = d; bestI[i] = code; }
      }
    }
  }
  __syncthreads();
#pragma unroll
  for (int i = 0; i < 8; ++i) {
    sh.r.rv[(ty * 8 + i) * 16 + tx] = bestV[i];
    sh.r.ri[(ty * 8 + i) * 16 + tx] = bestI[i];
  }
  __syncthreads();
  if (tid < BM) {
    float bv = sh.r.rv[tid * 16]; int bi = sh.r.ri[tid * 16];
    for (int t = 1; t < 16; ++t) {
      float v = sh.r.rv[tid * 16 + t]; int ii = sh.r.ri[tid * 16 + t];
      if (v < bv || (v == bv && ii < bi)) { bv = v; bi = ii; }
    }
    unsigned long long k64 = ((unsigned long long)__float_as_uint(bv) << 32) | (unsigned)bi;
    atomicMin(&key[row_base + tid], k64);
  }
}
// ---------- end fallback ----------

__global__ void scatter_k(const unsigned long long* __restrict__ key,
                          unsigned int* __restrict__ counts, float* __restrict__ out) {
  int row = blockIdx.x * 256 + threadIdx.x;
  int bi = (int)(unsigned int)(key[row] & 0xffffffffULL);
  out[OFF_IDX + row] = (float)bi;
  out[OFF_ENC + (size_t)row * K_CODES + bi] = 1.0f;
  atomicAdd(&counts[bi], 1u);
}

__global__ void quant_k(const float* __restrict__ z, const float* __restrict__ cb,
                        const unsigned long long* __restrict__ key, float* __restrict__ out,
                        double* __restrict__ losssum) {
  __shared__ double red[256];
  int bh = blockIdx.x, b = bh >> 6, h = bh & 63;
  int tid = threadIdx.x, w = tid & 63, c0 = tid >> 6;
  int n = (b << 12) + (h << 6) + w;
  int iv = (int)(unsigned int)(key[n] & 0xffffffffULL);
  const float* cbr = cb + (size_t)iv * D_DIM;
  size_t zoff = (size_t)b * CHW + (size_t)(h << 6) + w;
  double s = 0.0;
  for (int c = c0; c < D_DIM; c += 4) {
    float zv = z[zoff + (size_t)c * HW];
    float qv = cbr[c];
    float diff = qv - zv;
    out[OFF_QUANT + zoff + (size_t)c * HW] = zv + diff;   // STE forward rounding
    double dd = (double)qv - (double)zv;
    s += dd * dd;
  }
  red[tid] = s;
  __syncthreads();
  for (int st = 128; st > 0; st >>= 1) {
    if (tid < st) red[tid] += red[tid + st];
    __syncthreads();
  }
  if (tid == 0) atomicAdd(losssum, red[0]);
}

__global__ void final_k(const unsigned int* __restrict__ counts,
                        const double* __restrict__ losssum, float* __restrict__ out) {
  __shared__ double red[256];
  int tid = threadIdx.x;
  double s = 0.0;
  for (int k = tid; k < K_CODES; k += 256) {
    double p = (double)counts[k] / 32768.0;
    s += p * log(p + 1e-10);
  }
  red[tid] = s;
  __syncthreads();
  for (int st = 128; st > 0; st >>= 1) {
    if (tid < st) red[tid] += red[tid + st];
    __syncthreads();
  }
  if (tid == 0) {
    out[OFF_PERP] = (float)exp(-red[0]);
    out[OFF_LOSS] = (float)(1.25 * losssum[0] / 8388608.0);
  }
}

extern "C" void kernel_launch(void* const* d_in, const int* in_sizes, int n_in,
                              void* d_out, int out_size, void* d_ws, size_t ws_size,
                              hipStream_t stream) {
  (void)in_sizes; (void)n_in; (void)out_size;
  const float* z = (const float*)d_in[0];
  const float* cb = (const float*)d_in[1];
  float* out = (float*)d_out;
  float* ws = (float*)d_ws;

  float* rn = ws + WS_RN;
  float* en = ws + WS_EN;
  unsigned long long* key = (unsigned long long*)(ws + WS_KEY);
  unsigned int* counts = (unsigned int*)(ws + WS_CNT);
  double* losssum = (double*)(ws + WS_LOSS);

  hipMemsetAsync(out + OFF_ENC, 0, (size_t)N_ROWS * K_CODES * sizeof(float), stream);
  hipMemsetAsync(ws + WS_KEY, 0xFF, (size_t)N_ROWS * sizeof(unsigned long long), stream);

  enorm_k<<<K_CODES / 256, 256, 0, stream>>>(cb, en);

  if (ws_size >= WS_NEED_BYTES) {
    unsigned int* cnt2 = (unsigned int*)(ws + WS_CNT2);
    float* rowmin = ws + WS_THR;
    unsigned int* cand = (unsigned int*)(ws + WS_CAND);
    unsigned short* cbf = (unsigned short*)(ws + WS_CBF);
    // zero counts(4096) + loss(2) + counters + pad
    hipMemsetAsync(ws + WS_CNT, 0, (WS_THR - WS_CNT) * sizeof(float), stream);
    cbbf_k<<<(K_CODES * D_DIM / 4) / 256, 256, 0, stream>>>(cb, cbf);
    // SINGLE MFMA pass: fused exact rownorm + online emission + in-block re-cut.
    pass4f_k<<<N_ROWS / 64, 256, 0, stream>>>(z, cbf, en, rn, rowmin, cand, cnt2);
    verify_k<<<1024, 256, 0, stream>>>(z, cb, rn, en, cand, cnt2, key);
    // Guarded backstop: full exact recompute ONLY if the candidate list
    // overflowed (entries possibly dropped). Normally ~5 us of early-exit.
    argmin_fb<<<(N_ROWS / BM) * 4, 256, 0, stream>>>(z, cb, rn, en, key, cnt2);
  } else {
    rownorm_k<<<N_ROWS / 256, 256, 0, stream>>>(z, rn);
    hipMemsetAsync(ws + WS_CNT, 0, K_CODES * sizeof(unsigned int) + 2 * sizeof(double), stream);
    argmin_fb<<<(N_ROWS / BM) * 4, 256, 0, stream>>>(z, cb, rn, en, key, nullptr);
  }

  scatter_k<<<N_ROWS / 256, 256, 0, stream>>>(key, counts, out);
  quant_k<<<512, 256, 0, stream>>>(z, cb, key, out, losssum);
  final_k<<<1, 256, 0, stream>>>(counts, losssum, out);
}

// Round 8
// 836.801 us; speedup vs baseline: 1.1626x; 1.1223x over previous
//
#include <hip/hip_runtime.h>
#include <math.h>

// Problem constants
#define N_ROWS 32768      // B*H*W = 8*64*64
#define K_CODES 4096
#define D_DIM 256
#define HW 4096           // H*W
#define CHW 1048576       // C*H*W = 256*4096

// Output layout (float element offsets): loss(1) | quantized(8388608) | perplexity(1)
//                                        | encodings(32768*4096) | idx(32768)
#define OFF_LOSS  0
#define OFF_QUANT 1ULL
#define OFF_PERP  8388609ULL
#define OFF_ENC   8388610ULL
#define OFF_IDX   142606338ULL

// Workspace layout (float element offsets)
#define WS_RN   0           // 32768 row norms
#define WS_EN   32768       // 4096 code norms
#define WS_KEY  36864       // 32768 x u64 keys (d_bits<<32|code)
#define WS_CNT  102400      // 4096 uint counts
#define WS_LOSS 106496      // 1 double
#define WS_CCNT 106498      // (unused legacy slot)
#define WS_CNT2 106499      // candidate counter (u32)
#define WS_THR  106504      // 32768 per-row f32 final score min
#define WS_CAND 139272      // candidate list, CAP u32
#define CAP     1048576
#define WS_CBF  1187848     // codebook bf16 (1M shorts = 524288 floats); 16B aligned
#define WS_NEED_BYTES ((1187848ULL + 524288ULL) * 4ULL)   // ~6.85 MB (PROVEN to engage)

#define MARGIN 1.5e-3f      // worst-case |approx-exact| <= 2.8e-4 : 5x headroom
#define LBUF_N 1536         // per-block LDS pair buffer

typedef short bf16x8 __attribute__((ext_vector_type(8)));
typedef float f32x4 __attribute__((ext_vector_type(4)));
typedef float f32x2 __attribute__((ext_vector_type(2)));   // native vec: OK for nontemporal builtin

// fp32 -> bf16 RNE
__device__ __forceinline__ unsigned short f2bf(float f) {
  unsigned u = __float_as_uint(f);
  unsigned r = u + 0x7FFFu + ((u >> 16) & 1u);
  return (unsigned short)(r >> 16);
}

// async global->LDS, 16B per lane. LDS dest must be (wave-uniform base + lane*16).
__device__ __forceinline__ void async16(void* lds, const void* g) {
  typedef const __attribute__((address_space(1))) void* gvp;
  typedef __attribute__((address_space(3))) void* lvp;
  __builtin_amdgcn_global_load_lds((gvp)g, (lvp)lds, 16, 0, 0);
}

// numpy pairwise_sum replica for 128 squared elements (must stay bit-identical).
__device__ __forceinline__ float pairwise_sq_128(const float* __restrict__ p, int stride) {
  float r[8];
#pragma unroll
  for (int j = 0; j < 8; ++j) { float v = p[(size_t)j * stride]; r[j] = v * v; }
#pragma unroll
  for (int g = 1; g < 16; ++g) {
#pragma unroll
    for (int j = 0; j < 8; ++j) { float v = p[(size_t)(g * 8 + j) * stride]; r[j] += v * v; }
  }
  return ((r[0] + r[1]) + (r[2] + r[3])) + ((r[4] + r[5]) + (r[6] + r[7]));
}

__global__ void rownorm_k(const float* __restrict__ z, float* __restrict__ rn) {
  int row = blockIdx.x * 256 + threadIdx.x;
  const float* p = z + (size_t)(row >> 12) * CHW + (row & (HW - 1));
  rn[row] = pairwise_sq_128(p, HW) + pairwise_sq_128(p + (size_t)128 * HW, HW);
}

__global__ void enorm_k(const float* __restrict__ cb, float* __restrict__ en) {
  int k = blockIdx.x * 256 + threadIdx.x;
  const float* p = cb + (size_t)k * D_DIM;
  en[k] = pairwise_sq_128(p, 1) + pairwise_sq_128(p + 128, 1);
}

__global__ void cbbf_k(const float* __restrict__ cb, unsigned short* __restrict__ cbf) {
  int i = (blockIdx.x * 256 + threadIdx.x) * 4;
  float4 v = *(const float4*)(cb + i);
  unsigned d0 = f2bf(v.x) | ((unsigned)f2bf(v.y) << 16);
  unsigned d1 = f2bf(v.z) | ((unsigned)f2bf(v.w) << 16);
  *(int2*)(cbf + i) = make_int2((int)d0, (int)d1);
}

// Stage one 128-code x 64-dim bf16 B-tile (16 KB) into a double-buffer half,
// via 4 global_load_lds per thread. LDS layout is linear in chunk index i
// (dest = base + i*16B); the fragment swizzle is applied to the GLOBAL source
// address instead (m104/m173 pattern).
__device__ __forceinline__ void stageB(const unsigned short* __restrict__ cbf,
                                       short* bs, int tile, int ph2, int tid) {
#pragma unroll
  for (int k = 0; k < 4; ++k) {
    int i = tid + k * 256;
    int ks2 = i >> 9, s = i & 511;
    int ct = s >> 6, g = (s >> 4) & 3, m = s & 15;
    const unsigned short* src =
        cbf + (size_t)(tile * 128 + ct * 16 + m) * 256 + ph2 * 64 + ks2 * 32 + g * 8;
    async16(bs + (size_t)i * 8, src);
  }
}

// ============ SINGLE-PASS online filter (r6 structure + folded enc-zeroing) ============
// Block = 64 rows x ALL 4096 codes (32 tiles of 128). Pipelined B double-buffer,
// one barrier per 64-dim phase. During A-staging the fp32 z values are also
// squared into a 32 KB LDS scratch (reusing the not-yet-active B buffer) and
// 64 reducer threads replay numpy's pairwise tree BIT-EXACTLY -> rn[].
// Each block also zeroes its 1 MB slice of the encodings output with
// non-temporal f32x2 stores (16/thread/tile), folded under the MFMA pipeline —
// this replaces the serial 536 MB hipMemsetAsync (~85 us of pure write BW).
// scatter_k (the only enc consumer) launches after this kernel: ordering safe.
// Per tile: running row-min (incl. current tile), emit (pc, f32 score) into the
// LDS pair buffer when s <= running_rowmin + MARGIN (superset of the final-
// threshold set -> exact argmin always emitted). Block scans ALL codes of its
// rows, so it knows the FINAL rowmin at the end: re-cut the LDS pairs with the
// final threshold (bit-identical criterion to the proven second pass) and flush
// survivors via wave-aggregated compaction. LDS overflow spills raw pc to cand
// (conservative superset; verify_k absorbs).
__global__ __launch_bounds__(256, 2) void pass4g_k(
    const float* __restrict__ z, const unsigned short* __restrict__ cbf,
    const float* __restrict__ en, float* __restrict__ rn,
    float* __restrict__ rowmin, float* __restrict__ enc,
    unsigned int* __restrict__ cand, unsigned int* __restrict__ cnt2) {
  __shared__ __align__(16) short ASw[4 * 8 * 64 * 8];   // 32 KB
  __shared__ __align__(16) short BS2[2 * 1024 * 8];     // 32 KB (scratch during A-stage)
  __shared__ unsigned int lbuf[2 * LBUF_N];             // 12 KB pairs (pc, score)
  __shared__ float rmf[64];                             // rn half-0 temp, later final row min
  __shared__ unsigned int lcnt;

  const int tid = threadIdx.x;
  const int lane = tid & 63;
  const int w = tid >> 6;                 // wave id = row-tile
  const int row_base = blockIdx.x * 64;
  const float* zb = z + (size_t)(row_base >> 12) * CHW + (row_base & (HW - 1));

  if (tid == 0) lcnt = 0;

  // ---- Stage A: 64 rows x 256 dims, fp32->bf16, swizzled to A-frag order,
  //      plus exact-square partials for the fused rownorm ----
  {
    float* pf = (float*)BS2;              // 16 g-groups x 64 rows x 8 lanes = 32 KB
    int f4 = tid & 15;
    int r0 = f4 * 4;
    int g16 = tid >> 4;                   // pairwise g-group (per half)
#pragma unroll
    for (int it = 0; it < 2; ++it) {
      int c_oct = (tid >> 4) + it * 16;   // 8-dim octet 0..31
      float4 v[8];
#pragma unroll
      for (int j = 0; j < 8; ++j)
        v[j] = *(const float4*)(zb + (size_t)(c_oct * 8 + j) * HW + r0);
      int s = c_oct >> 2, g = c_oct & 3;
#pragma unroll
      for (int i = 0; i < 4; ++i) {
        int r = r0 + i, rt = r >> 4, m = r & 15;
        int dw[4];
#pragma unroll
        for (int k = 0; k < 4; ++k) {
          unsigned lo = f2bf(((const float*)&v[2 * k])[i]);
          unsigned hi = f2bf(((const float*)&v[2 * k + 1])[i]);
          dw[k] = (int)(lo | (hi << 16));
        }
        *(int4*)&ASw[(((rt * 8 + s) * 64) + g * 16 + m) * 8] =
            make_int4(dw[0], dw[1], dw[2], dw[3]);
        // exact squares (fp32, element-wise identical to rownorm_k's v*v)
#pragma unroll
        for (int j = 0; j < 8; ++j) {
          float x = ((const float*)&v[j])[i];
          pf[(g16 * 64 + r) * 8 + j] = x * x;
        }
      }
      __syncthreads();
      // 64 reducers: numpy pairwise tree, bit-exact (sequential g, same fold)
      if (tid < 64) {
        float racc[8];
#pragma unroll
        for (int j = 0; j < 8; ++j) racc[j] = pf[(size_t)tid * 8 + j];
        for (int gg = 1; gg < 16; ++gg)
#pragma unroll
          for (int j = 0; j < 8; ++j) racc[j] += pf[(gg * 64 + tid) * 8 + j];
        float h = ((racc[0] + racc[1]) + (racc[2] + racc[3])) +
                  ((racc[4] + racc[5]) + (racc[6] + racc[7]));
        if (it == 0) rmf[tid] = h;                      // first 128-dim half
        else rn[row_base + tid] = rmf[tid] + h;         // + second half (ref order)
      }
      __syncthreads();
    }
  }

  unsigned rowenc[4];
#pragma unroll
  for (int r = 0; r < 4; ++r)
    rowenc[r] = (unsigned)(row_base + w * 16 + (lane >> 4) * 4 + r) << 12;

  float rmin[4] = {3.4e38f, 3.4e38f, 3.4e38f, 3.4e38f};

  stageB(cbf, BS2, 0, 0, tid);            // prologue prefetch into buf 0
  int pidx = 0;
  for (int tile = 0; tile < 32; ++tile) {
    float ev[8];
#pragma unroll
    for (int ct = 0; ct < 8; ++ct) ev[ct] = en[tile * 128 + ct * 16 + (lane & 15)];

    f32x4 acc[8];
#pragma unroll
    for (int ct = 0; ct < 8; ++ct) acc[ct] = (f32x4){0.f, 0.f, 0.f, 0.f};

#pragma unroll
    for (int ph2 = 0; ph2 < 4; ++ph2, ++pidx) {
      __syncthreads();   // drains my prefetch (implicit vmcnt(0)); buf^1 free
      int nx = pidx + 1;
      if (nx < 128) stageB(cbf, BS2 + (nx & 1) * 8192, nx >> 2, nx & 3, tid);

      const short* bb = BS2 + (pidx & 1) * 8192;
      bf16x8 a0 = *(const bf16x8*)&ASw[((w * 8 + ph2 * 2 + 0) * 64 + lane) * 8];
      bf16x8 a1 = *(const bf16x8*)&ASw[((w * 8 + ph2 * 2 + 1) * 64 + lane) * 8];
      __builtin_amdgcn_s_setprio(1);
#pragma unroll
      for (int ct = 0; ct < 8; ++ct) {
        bf16x8 b0 = *(const bf16x8*)&bb[(ct * 64 + lane) * 8];
        acc[ct] = __builtin_amdgcn_mfma_f32_16x16x32_bf16(a0, b0, acc[ct], 0, 0, 0);
      }
#pragma unroll
      for (int ct = 0; ct < 8; ++ct) {
        bf16x8 b1 = *(const bf16x8*)&bb[(512 + ct * 64 + lane) * 8];
        acc[ct] = __builtin_amdgcn_mfma_f32_16x16x32_bf16(a1, b1, acc[ct], 0, 0, 0);
      }
      __builtin_amdgcn_s_setprio(0);
    }

    // ---- folded enc-zeroing: this block's 1 MB slice, 32 KB per tile ----
    // (non-temporal f32x2: OFF_ENC is 8B-aligned; stores hide under MFMA)
    {
      f32x2 zz = (f32x2){0.f, 0.f};
      f32x2* dst = (f32x2*)enc + ((size_t)blockIdx.x * 32 + tile) * 4096 + tid;
#pragma unroll
      for (int k = 0; k < 16; ++k)
        __builtin_nontemporal_store(zz, dst + k * 256);
    }

    // ---- tile epilogue: running min (incl. this tile) -> threshold -> emit ----
#pragma unroll
    for (int ct = 0; ct < 8; ++ct)
#pragma unroll
      for (int r = 0; r < 4; ++r)
        rmin[r] = fminf(rmin[r], ev[ct] - 2.0f * acc[ct][r]);

    float thr2[4];
#pragma unroll
    for (int r = 0; r < 4; ++r) {
      float v = rmin[r];
      v = fminf(v, __shfl_xor(v, 1));
      v = fminf(v, __shfl_xor(v, 2));
      v = fminf(v, __shfl_xor(v, 4));
      v = fminf(v, __shfl_xor(v, 8));
      thr2[r] = v + MARGIN;
    }

#pragma unroll
    for (int ct = 0; ct < 8; ++ct) {
      unsigned code = (unsigned)(tile * 128 + ct * 16 + (lane & 15));
#pragma unroll
      for (int r = 0; r < 4; ++r) {
        float s = ev[ct] - 2.0f * acc[ct][r];
        if (s <= thr2[r]) {
          unsigned pc = rowenc[r] | code;
          unsigned pos = atomicAdd(&lcnt, 1u);
          if (pos < LBUF_N) {
            lbuf[2 * pos] = pc;
            lbuf[2 * pos + 1] = __float_as_uint(s);
          } else {
            // rare spill: conservative (skips final re-cut); verify absorbs
            unsigned g = atomicAdd(cnt2, 1u);
            if (g < CAP) cand[g] = pc;
          }
        }
      }
    }
  }

  // Final per-row min -> global rowmin + LDS rmf (block owns its rows).
#pragma unroll
  for (int r = 0; r < 4; ++r) {
    float v = rmin[r];
    v = fminf(v, __shfl_xor(v, 1));
    v = fminf(v, __shfl_xor(v, 2));
    v = fminf(v, __shfl_xor(v, 4));
    v = fminf(v, __shfl_xor(v, 8));
    if ((lane & 15) == 0) {
      unsigned row = rowenc[r] >> 12;
      rowmin[row] = v;
      rmf[row & 63] = v;
    }
  }

  // Re-cut LDS pairs against the FINAL threshold; wave-aggregated compaction.
  __syncthreads();
  unsigned n = lcnt; if (n > LBUF_N) n = LBUF_N;
  for (unsigned i0 = 0; i0 < n; i0 += 256) {
    unsigned i = i0 + tid;
    bool keep = false; unsigned pc = 0;
    if (i < n) {
      pc = lbuf[2 * i];
      float s = __uint_as_float(lbuf[2 * i + 1]);
      keep = (s <= rmf[(pc >> 12) & 63] + MARGIN);   // == proven pass-2 criterion
    }
    unsigned long long m = __ballot(keep);
    unsigned wb = 0;
    if ((tid & 63) == 0 && m) wb = atomicAdd(cnt2, (unsigned)__popcll(m));
    wb = __shfl(wb, 0);
    if (keep) {
      unsigned off = (unsigned)__popcll(m & ((1ull << (tid & 63)) - 1ull));
      unsigned g = wb + off;
      if (g < CAP) cand[g] = pc;
    }
  }
}

// Exact re-verify: replay the exact fp32 fmaf chain (bit-identical to fallback).
__global__ void verify_k(const float* __restrict__ z, const float* __restrict__ cb,
                         const float* __restrict__ rn, const float* __restrict__ en,
                         const unsigned int* __restrict__ cand,
                         const unsigned int* __restrict__ cnt,
                         unsigned long long* __restrict__ key) {
  unsigned total = *cnt; if (total > CAP) total = CAP;
  for (unsigned i = blockIdx.x * 256 + threadIdx.x; i < total; i += gridDim.x * 256) {
    unsigned pc = cand[i];
    unsigned row = pc >> 12, code = pc & 4095u;
    const float* x = z + (size_t)(row >> 12) * CHW + (row & (HW - 1));
    const float* e = cb + (size_t)code * D_DIM;
    float acc = 0.0f;
#pragma unroll 8
    for (int c = 0; c < D_DIM; ++c) acc = fmaf(x[(size_t)c * HW], e[c], acc);
    float d = (rn[row] + en[code]) - 2.0f * acc;   // reference rounding order
    unsigned long long k64 = ((unsigned long long)__float_as_uint(d) << 32) | code;
    atomicMin(&key[row], k64);
  }
}

// ---------- fp32 argmin (small-ws fallback AND guarded backstop) ----------
// guard != nullptr: early-exit unless the candidate counter overflowed CAP
// (i.e., candidates may have been dropped) -> recompute everything exactly.
#define BM 128
#define BN 128
#define BK 32
#define KQ 1024
#define ES_S 36
__global__ __launch_bounds__(256, 3) void argmin_fb(
    const float* __restrict__ z, const float* __restrict__ cb,
    const float* __restrict__ rn, const float* __restrict__ en,
    unsigned long long* __restrict__ key, const unsigned int* __restrict__ guard) {
  if (guard && *guard <= CAP) return;
  __shared__ union {
    struct { float Xs[BK * BM]; float Es[BN * ES_S]; } s;
    struct { float rv[BM * 16]; int ri[BM * 16]; } r;
  } sh;
  const int tid = threadIdx.x;
  const int tx = tid & 15, ty = tid >> 4;
  const int row_base = (blockIdx.x >> 2) * BM;
  const int q = blockIdx.x & 3;
  const float* zb = z + (size_t)(row_base >> 12) * CHW + (row_base & (HW - 1));
  float rnv[8];
#pragma unroll
  for (int i = 0; i < 8; ++i) rnv[i] = rn[row_base + ty * 8 + i];
  float bestV[8]; int bestI[8];
#pragma unroll
  for (int i = 0; i < 8; ++i) { bestV[i] = 3.4e38f; bestI[i] = 0; }
  for (int t0 = q * KQ; t0 < q * KQ + KQ; t0 += BN) {
    float acc[8][8];
#pragma unroll
    for (int i = 0; i < 8; ++i)
#pragma unroll
      for (int j = 0; j < 8; ++j) acc[i][j] = 0.0f;
    for (int kb = 0; kb < D_DIM; kb += BK) {
      __syncthreads();
#pragma unroll
      for (int k = 0; k < 4; ++k) {
        int l4 = tid + k * 256, cl = l4 >> 5, ro = (l4 & 31) << 2;
        *(float4*)&sh.s.Xs[cl * BM + ro] = *(const float4*)(zb + (size_t)(kb + cl) * HW + ro);
      }
#pragma unroll
      for (int k = 0; k < 4; ++k) {
        int l4 = tid + k * 256, kl = l4 >> 3, cq = (l4 & 7) << 2;
        *(float4*)&sh.s.Es[kl * ES_S + cq] =
            *(const float4*)(cb + (size_t)(t0 + kl) * D_DIM + kb + cq);
      }
      __syncthreads();
#pragma unroll
      for (int c4 = 0; c4 < BK / 4; ++c4) {
        float4 ef[8];
#pragma unroll
        for (int j = 0; j < 8; ++j)
          ef[j] = *(const float4*)&sh.s.Es[(tx + 16 * j) * ES_S + c4 * 4];
#pragma unroll
        for (int cc = 0; cc < 4; ++cc) {
          int c = c4 * 4 + cc;
          float4 xa = *(const float4*)&sh.s.Xs[c * BM + ty * 8];
          float4 xb = *(const float4*)&sh.s.Xs[c * BM + ty * 8 + 4];
          float xv[8] = {xa.x, xa.y, xa.z, xa.w, xb.x, xb.y, xb.z, xb.w};
          float evv[8] = {((const float*)&ef[0])[cc], ((const float*)&ef[1])[cc],
                          ((const float*)&ef[2])[cc], ((const float*)&ef[3])[cc],
                          ((const float*)&ef[4])[cc], ((const float*)&ef[5])[cc],
                          ((const float*)&ef[6])[cc], ((const float*)&ef[7])[cc]};
#pragma unroll
          for (int i = 0; i < 8; ++i)
#pragma unroll
            for (int j = 0; j < 8; ++j) acc[i][j] = fmaf(xv[i], evv[j], acc[i][j]);
        }
      }
    }
#pragma unroll
    for (int j = 0; j < 8; ++j) {
      int code = t0 + tx + 16 * j;
      float ev = en[code];
#pragma unroll
      for (int i = 0; i < 8; ++i) {
        float d = (rnv[i] + ev) - 2.0f * acc[i][j];
        if (d < bestV[i]) { bestV[i] = d; bestI[i] = code; }
      }
    }
  }
  __syncthreads();
#pragma unroll
  for (int i = 0; i < 8; ++i) {
    sh.r.rv[(ty * 8 + i) * 16 + tx] = bestV[i];
    sh.r.ri[(ty * 8 + i) * 16 + tx] = bestI[i];
  }
  __syncthreads();
  if (tid < BM) {
    float bv = sh.r.rv[tid * 16]; int bi = sh.r.ri[tid * 16];
    for (int t = 1; t < 16; ++t) {
      float v = sh.r.rv[tid * 16 + t]; int ii = sh.r.ri[tid * 16 + t];
      if (v < bv || (v == bv && ii < bi)) { bv = v; bi = ii; }
    }
    unsigned long long k64 = ((unsigned long long)__float_as_uint(bv) << 32) | (unsigned)bi;
    atomicMin(&key[row_base + tid], k64);
  }
}
// ---------- end fallback ----------

__global__ void scatter_k(const unsigned long long* __restrict__ key,
                          unsigned int* __restrict__ counts, float* __restrict__ out) {
  int row = blockIdx.x * 256 + threadIdx.x;
  int bi = (int)(unsigned int)(key[row] & 0xffffffffULL);
  out[OFF_IDX + row] = (float)bi;
  out[OFF_ENC + (size_t)row * K_CODES + bi] = 1.0f;
  atomicAdd(&counts[bi], 1u);
}

__global__ void quant_k(const float* __restrict__ z, const float* __restrict__ cb,
                        const unsigned long long* __restrict__ key, float* __restrict__ out,
                        double* __restrict__ losssum) {
  __shared__ double red[256];
  int bh = blockIdx.x, b = bh >> 6, h = bh & 63;
  int tid = threadIdx.x, w = tid & 63, c0 = tid >> 6;
  int n = (b << 12) + (h << 6) + w;
  int iv = (int)(unsigned int)(key[n] & 0xffffffffULL);
  const float* cbr = cb + (size_t)iv * D_DIM;
  size_t zoff = (size_t)b * CHW + (size_t)(h << 6) + w;
  double s = 0.0;
  for (int c = c0; c < D_DIM; c += 4) {
    float zv = z[zoff + (size_t)c * HW];
    float qv = cbr[c];
    float diff = qv - zv;
    out[OFF_QUANT + zoff + (size_t)c * HW] = zv + diff;   // STE forward rounding
    double dd = (double)qv - (double)zv;
    s += dd * dd;
  }
  red[tid] = s;
  __syncthreads();
  for (int st = 128; st > 0; st >>= 1) {
    if (tid < st) red[tid] += red[tid + st];
    __syncthreads();
  }
  if (tid == 0) atomicAdd(losssum, red[0]);
}

__global__ void final_k(const unsigned int* __restrict__ counts,
                        const double* __restrict__ losssum, float* __restrict__ out) {
  __shared__ double red[256];
  int tid = threadIdx.x;
  double s = 0.0;
  for (int k = tid; k < K_CODES; k += 256) {
    double p = (double)counts[k] / 32768.0;
    s += p * log(p + 1e-10);
  }
  red[tid] = s;
  __syncthreads();
  for (int st = 128; st > 0; st >>= 1) {
    if (tid < st) red[tid] += red[tid + st];
    __syncthreads();
  }
  if (tid == 0) {
    out[OFF_PERP] = (float)exp(-red[0]);
    out[OFF_LOSS] = (float)(1.25 * losssum[0] / 8388608.0);
  }
}

extern "C" void kernel_launch(void* const* d_in, const int* in_sizes, int n_in,
                              void* d_out, int out_size, void* d_ws, size_t ws_size,
                              hipStream_t stream) {
  (void)in_sizes; (void)n_in; (void)out_size;
  const float* z = (const float*)d_in[0];
  const float* cb = (const float*)d_in[1];
  float* out = (float*)d_out;
  float* ws = (float*)d_ws;

  float* rn = ws + WS_RN;
  float* en = ws + WS_EN;
  unsigned long long* key = (unsigned long long*)(ws + WS_KEY);
  unsigned int* counts = (unsigned int*)(ws + WS_CNT);
  double* losssum = (double*)(ws + WS_LOSS);

  hipMemsetAsync(ws + WS_KEY, 0xFF, (size_t)N_ROWS * sizeof(unsigned long long), stream);

  enorm_k<<<K_CODES / 256, 256, 0, stream>>>(cb, en);

  if (ws_size >= WS_NEED_BYTES) {
    unsigned int* cnt2 = (unsigned int*)(ws + WS_CNT2);
    float* rowmin = ws + WS_THR;
    unsigned int* cand = (unsigned int*)(ws + WS_CAND);
    unsigned short* cbf = (unsigned short*)(ws + WS_CBF);
    // zero counts(4096) + loss(2) + counters + pad
    hipMemsetAsync(ws + WS_CNT, 0, (WS_THR - WS_CNT) * sizeof(float), stream);
    cbbf_k<<<(K_CODES * D_DIM / 4) / 256, 256, 0, stream>>>(cb, cbf);
    // SINGLE MFMA pass: fused rownorm + folded enc-zeroing + online emission
    // + in-block re-cut. (enc memset is folded into the pass's tile loop.)
    pass4g_k<<<N_ROWS / 64, 256, 0, stream>>>(z, cbf, en, rn, rowmin,
                                              out + OFF_ENC, cand, cnt2);
    verify_k<<<1024, 256, 0, stream>>>(z, cb, rn, en, cand, cnt2, key);
    // Guarded backstop: full exact recompute ONLY if the candidate list
    // overflowed (entries possibly dropped). Normally ~5 us of early-exit.
    argmin_fb<<<(N_ROWS / BM) * 4, 256, 0, stream>>>(z, cb, rn, en, key, cnt2);
  } else {
    hipMemsetAsync(out + OFF_ENC, 0, (size_t)N_ROWS * K_CODES * sizeof(float), stream);
    rownorm_k<<<N_ROWS / 256, 256, 0, stream>>>(z, rn);
    hipMemsetAsync(ws + WS_CNT, 0, K_CODES * sizeof(unsigned int) + 2 * sizeof(double), stream);
    argmin_fb<<<(N_ROWS / BM) * 4, 256, 0, stream>>>(z, cb, rn, en, key, nullptr);
  }

  scatter_k<<<N_ROWS / 256, 256, 0, stream>>>(key, counts, out);
  quant_k<<<512, 256, 0, stream>>>(z, cb, key, out, losssum);
  final_k<<<1, 256, 0, stream>>>(counts, losssum, out);
}

// Round 9
// 760.172 us; speedup vs baseline: 1.2798x; 1.1008x over previous
//
#include <hip/hip_runtime.h>
#include <math.h>

// Problem constants
#define N_ROWS 32768      // B*H*W = 8*64*64
#define K_CODES 4096
#define D_DIM 256
#define HW 4096           // H*W
#define CHW 1048576       // C*H*W = 256*4096

// Output layout (float element offsets): loss(1) | quantized(8388608) | perplexity(1)
//                                        | encodings(32768*4096) | idx(32768)
#define OFF_LOSS  0
#define OFF_QUANT 1ULL
#define OFF_PERP  8388609ULL
#define OFF_ENC   8388610ULL
#define OFF_IDX   142606338ULL

// Workspace layout (float element offsets)
#define WS_RN   0           // 32768 row norms
#define WS_EN   32768       // 4096 code norms
#define WS_KEY  36864       // 32768 x u64 keys (d_bits<<32|code)
#define WS_CNT  102400      // 4096 uint counts
#define WS_LOSS 106496      // 1 double
#define WS_CCNT 106498      // (unused legacy slot)
#define WS_CNT2 106499      // spill-candidate counter (u32)
#define WS_THR  106504      // (legacy rowmin slot, unused)
#define WS_CAND 139272      // spill candidate list, CAP u32
#define CAP     1048576
#define WS_CBF  1187848     // codebook bf16 (1M shorts = 524288 floats); 16B aligned
#define WS_NEED_BYTES ((1187848ULL + 524288ULL) * 4ULL)   // ~6.85 MB (PROVEN to engage)

#define MARGIN 1.5e-3f      // worst-case |approx-exact| <= 2.8e-4 : 5x headroom
#define LBUF_N 1536         // per-block LDS pair buffer
#define CBUF_N 640          // per-block compacted-survivor buffer (~190 expected)

typedef short bf16x8 __attribute__((ext_vector_type(8)));
typedef float f32x4 __attribute__((ext_vector_type(4)));
typedef float f32x2 __attribute__((ext_vector_type(2)));   // native vec: OK for nontemporal builtin

// fp32 -> bf16 RNE
__device__ __forceinline__ unsigned short f2bf(float f) {
  unsigned u = __float_as_uint(f);
  unsigned r = u + 0x7FFFu + ((u >> 16) & 1u);
  return (unsigned short)(r >> 16);
}

// async global->LDS, 16B per lane. LDS dest must be (wave-uniform base + lane*16).
__device__ __forceinline__ void async16(void* lds, const void* g) {
  typedef const __attribute__((address_space(1))) void* gvp;
  typedef __attribute__((address_space(3))) void* lvp;
  __builtin_amdgcn_global_load_lds((gvp)g, (lvp)lds, 16, 0, 0);
}

// numpy pairwise_sum replica for 128 squared elements (must stay bit-identical).
__device__ __forceinline__ float pairwise_sq_128(const float* __restrict__ p, int stride) {
  float r[8];
#pragma unroll
  for (int j = 0; j < 8; ++j) { float v = p[(size_t)j * stride]; r[j] = v * v; }
#pragma unroll
  for (int g = 1; g < 16; ++g) {
#pragma unroll
    for (int j = 0; j < 8; ++j) { float v = p[(size_t)(g * 8 + j) * stride]; r[j] += v * v; }
  }
  return ((r[0] + r[1]) + (r[2] + r[3])) + ((r[4] + r[5]) + (r[6] + r[7]));
}

__global__ void rownorm_k(const float* __restrict__ z, float* __restrict__ rn) {
  int row = blockIdx.x * 256 + threadIdx.x;
  const float* p = z + (size_t)(row >> 12) * CHW + (row & (HW - 1));
  rn[row] = pairwise_sq_128(p, HW) + pairwise_sq_128(p + (size_t)128 * HW, HW);
}

__global__ void enorm_k(const float* __restrict__ cb, float* __restrict__ en) {
  int k = blockIdx.x * 256 + threadIdx.x;
  const float* p = cb + (size_t)k * D_DIM;
  en[k] = pairwise_sq_128(p, 1) + pairwise_sq_128(p + 128, 1);
}

__global__ void cbbf_k(const float* __restrict__ cb, unsigned short* __restrict__ cbf) {
  int i = (blockIdx.x * 256 + threadIdx.x) * 4;
  float4 v = *(const float4*)(cb + i);
  unsigned d0 = f2bf(v.x) | ((unsigned)f2bf(v.y) << 16);
  unsigned d1 = f2bf(v.z) | ((unsigned)f2bf(v.w) << 16);
  *(int2*)(cbf + i) = make_int2((int)d0, (int)d1);
}

// Stage one 128-code x 64-dim bf16 B-tile (16 KB) into a double-buffer half,
// via 4 global_load_lds per thread. LDS layout is linear in chunk index i
// (dest = base + i*16B); the fragment swizzle is applied to the GLOBAL source
// address instead (m104/m173 pattern).
__device__ __forceinline__ void stageB(const unsigned short* __restrict__ cbf,
                                       short* bs, int tile, int ph2, int tid) {
#pragma unroll
  for (int k = 0; k < 4; ++k) {
    int i = tid + k * 256;
    int ks2 = i >> 9, s = i & 511;
    int ct = s >> 6, g = (s >> 4) & 3, m = s & 15;
    const unsigned short* src =
        cbf + (size_t)(tile * 128 + ct * 16 + m) * 256 + ph2 * 64 + ks2 * 32 + g * 8;
    async16(bs + (size_t)i * 8, src);
  }
}

// ==== SINGLE-PASS: filter + fused rownorm + folded enc-zeroing + IN-BLOCK VERIFY ====
// Block = 64 rows x ALL 4096 codes (32 tiles of 128). Pipelined B double-buffer,
// one barrier per 64-dim phase. A-staging also computes rn[] bit-exactly (numpy
// pairwise tree) and keeps an LDS copy rn_s. Each block zeroes its 1 MB slice of
// the encodings output (non-temporal f32x2, folded under MFMA). Per tile:
// running row-min, emit (pc, f32 score) when s <= running_rowmin + MARGIN
// (superset of final-threshold set -> exact argmin always emitted). At the end
// the block knows the FINAL rowmin: re-cut pairs (bit-identical criterion),
// compact survivors into LDS cbuf, then verify them IN-BLOCK with the exact
// fp32 fmaf chain (bit-identical to verify_k) and atomicMin into key[].
// Overflows (lbuf or cbuf) spill raw pc to cand/cnt2 -> tiny verify_k absorbs;
// cnt2 > CAP triggers the full argmin_fb backstop.
__global__ __launch_bounds__(256, 2) void pass5v_k(
    const float* __restrict__ z, const float* __restrict__ cb,
    const unsigned short* __restrict__ cbf,
    const float* __restrict__ en, float* __restrict__ rn,
    float* __restrict__ enc, unsigned long long* __restrict__ key,
    unsigned int* __restrict__ cand, unsigned int* __restrict__ cnt2) {
  __shared__ __align__(16) short ASw[4 * 8 * 64 * 8];   // 32 KB
  __shared__ __align__(16) short BS2[2 * 1024 * 8];     // 32 KB (scratch during A-stage)
  __shared__ unsigned int lbuf[2 * LBUF_N];             // 12 KB pairs (pc, score)
  __shared__ unsigned int cbuf[CBUF_N];                 // 2.5 KB survivors
  __shared__ float rmf[64];                             // rn half-0 temp, later final row min
  __shared__ float rn_s[64];                            // exact rn copy (for in-block verify)
  __shared__ unsigned int lcnt, ccnt;

  const int tid = threadIdx.x;
  const int lane = tid & 63;
  const int w = tid >> 6;                 // wave id = row-tile
  const int row_base = blockIdx.x * 64;
  const float* zb = z + (size_t)(row_base >> 12) * CHW + (row_base & (HW - 1));

  if (tid == 0) { lcnt = 0; ccnt = 0; }

  // ---- Stage A: 64 rows x 256 dims, fp32->bf16, swizzled to A-frag order,
  //      plus exact-square partials for the fused rownorm ----
  {
    float* pf = (float*)BS2;              // 16 g-groups x 64 rows x 8 lanes = 32 KB
    int f4 = tid & 15;
    int r0 = f4 * 4;
    int g16 = tid >> 4;                   // pairwise g-group (per half)
#pragma unroll
    for (int it = 0; it < 2; ++it) {
      int c_oct = (tid >> 4) + it * 16;   // 8-dim octet 0..31
      float4 v[8];
#pragma unroll
      for (int j = 0; j < 8; ++j)
        v[j] = *(const float4*)(zb + (size_t)(c_oct * 8 + j) * HW + r0);
      int s = c_oct >> 2, g = c_oct & 3;
#pragma unroll
      for (int i = 0; i < 4; ++i) {
        int r = r0 + i, rt = r >> 4, m = r & 15;
        int dw[4];
#pragma unroll
        for (int k = 0; k < 4; ++k) {
          unsigned lo = f2bf(((const float*)&v[2 * k])[i]);
          unsigned hi = f2bf(((const float*)&v[2 * k + 1])[i]);
          dw[k] = (int)(lo | (hi << 16));
        }
        *(int4*)&ASw[(((rt * 8 + s) * 64) + g * 16 + m) * 8] =
            make_int4(dw[0], dw[1], dw[2], dw[3]);
        // exact squares (fp32, element-wise identical to rownorm_k's v*v)
#pragma unroll
        for (int j = 0; j < 8; ++j) {
          float x = ((const float*)&v[j])[i];
          pf[(g16 * 64 + r) * 8 + j] = x * x;
        }
      }
      __syncthreads();
      // 64 reducers: numpy pairwise tree, bit-exact (sequential g, same fold)
      if (tid < 64) {
        float racc[8];
#pragma unroll
        for (int j = 0; j < 8; ++j) racc[j] = pf[(size_t)tid * 8 + j];
        for (int gg = 1; gg < 16; ++gg)
#pragma unroll
          for (int j = 0; j < 8; ++j) racc[j] += pf[(gg * 64 + tid) * 8 + j];
        float h = ((racc[0] + racc[1]) + (racc[2] + racc[3])) +
                  ((racc[4] + racc[5]) + (racc[6] + racc[7]));
        if (it == 0) rmf[tid] = h;                      // first 128-dim half
        else {
          float tot = rmf[tid] + h;                     // + second half (ref order)
          rn[row_base + tid] = tot;
          rn_s[tid] = tot;
        }
      }
      __syncthreads();
    }
  }

  unsigned rowenc[4];
#pragma unroll
  for (int r = 0; r < 4; ++r)
    rowenc[r] = (unsigned)(row_base + w * 16 + (lane >> 4) * 4 + r) << 12;

  float rmin[4] = {3.4e38f, 3.4e38f, 3.4e38f, 3.4e38f};

  stageB(cbf, BS2, 0, 0, tid);            // prologue prefetch into buf 0
  int pidx = 0;
  for (int tile = 0; tile < 32; ++tile) {
    float ev[8];
#pragma unroll
    for (int ct = 0; ct < 8; ++ct) ev[ct] = en[tile * 128 + ct * 16 + (lane & 15)];

    f32x4 acc[8];
#pragma unroll
    for (int ct = 0; ct < 8; ++ct) acc[ct] = (f32x4){0.f, 0.f, 0.f, 0.f};

#pragma unroll
    for (int ph2 = 0; ph2 < 4; ++ph2, ++pidx) {
      __syncthreads();   // drains my prefetch (implicit vmcnt(0)); buf^1 free
      int nx = pidx + 1;
      if (nx < 128) stageB(cbf, BS2 + (nx & 1) * 8192, nx >> 2, nx & 3, tid);

      const short* bb = BS2 + (pidx & 1) * 8192;
      bf16x8 a0 = *(const bf16x8*)&ASw[((w * 8 + ph2 * 2 + 0) * 64 + lane) * 8];
      bf16x8 a1 = *(const bf16x8*)&ASw[((w * 8 + ph2 * 2 + 1) * 64 + lane) * 8];
      __builtin_amdgcn_s_setprio(1);
#pragma unroll
      for (int ct = 0; ct < 8; ++ct) {
        bf16x8 b0 = *(const bf16x8*)&bb[(ct * 64 + lane) * 8];
        acc[ct] = __builtin_amdgcn_mfma_f32_16x16x32_bf16(a0, b0, acc[ct], 0, 0, 0);
      }
#pragma unroll
      for (int ct = 0; ct < 8; ++ct) {
        bf16x8 b1 = *(const bf16x8*)&bb[(512 + ct * 64 + lane) * 8];
        acc[ct] = __builtin_amdgcn_mfma_f32_16x16x32_bf16(a1, b1, acc[ct], 0, 0, 0);
      }
      __builtin_amdgcn_s_setprio(0);
    }

    // ---- folded enc-zeroing: this block's 1 MB slice, 32 KB per tile ----
    {
      f32x2 zz = (f32x2){0.f, 0.f};
      f32x2* dst = (f32x2*)enc + ((size_t)blockIdx.x * 32 + tile) * 4096 + tid;
#pragma unroll
      for (int k = 0; k < 16; ++k)
        __builtin_nontemporal_store(zz, dst + k * 256);
    }

    // ---- tile epilogue: running min (incl. this tile) -> threshold -> emit ----
#pragma unroll
    for (int ct = 0; ct < 8; ++ct)
#pragma unroll
      for (int r = 0; r < 4; ++r)
        rmin[r] = fminf(rmin[r], ev[ct] - 2.0f * acc[ct][r]);

    float thr2[4];
#pragma unroll
    for (int r = 0; r < 4; ++r) {
      float v = rmin[r];
      v = fminf(v, __shfl_xor(v, 1));
      v = fminf(v, __shfl_xor(v, 2));
      v = fminf(v, __shfl_xor(v, 4));
      v = fminf(v, __shfl_xor(v, 8));
      thr2[r] = v + MARGIN;
    }

#pragma unroll
    for (int ct = 0; ct < 8; ++ct) {
      unsigned code = (unsigned)(tile * 128 + ct * 16 + (lane & 15));
#pragma unroll
      for (int r = 0; r < 4; ++r) {
        float s = ev[ct] - 2.0f * acc[ct][r];
        if (s <= thr2[r]) {
          unsigned pc = rowenc[r] | code;
          unsigned pos = atomicAdd(&lcnt, 1u);
          if (pos < LBUF_N) {
            lbuf[2 * pos] = pc;
            lbuf[2 * pos + 1] = __float_as_uint(s);
          } else {
            // rare spill: skips re-cut; tiny verify_k absorbs
            unsigned g = atomicAdd(cnt2, 1u);
            if (g < CAP) cand[g] = pc;
          }
        }
      }
    }
  }

  // Final per-row min -> LDS rmf (block owns its rows exclusively).
#pragma unroll
  for (int r = 0; r < 4; ++r) {
    float v = rmin[r];
    v = fminf(v, __shfl_xor(v, 1));
    v = fminf(v, __shfl_xor(v, 2));
    v = fminf(v, __shfl_xor(v, 4));
    v = fminf(v, __shfl_xor(v, 8));
    if ((lane & 15) == 0) rmf[(rowenc[r] >> 12) & 63] = v;
  }

  // Re-cut pairs against the FINAL threshold; compact survivors into LDS cbuf.
  __syncthreads();
  unsigned n = lcnt; if (n > LBUF_N) n = LBUF_N;
  for (unsigned i0 = 0; i0 < n; i0 += 256) {
    unsigned i = i0 + tid;
    bool keep = false; unsigned pc = 0;
    if (i < n) {
      pc = lbuf[2 * i];
      float s = __uint_as_float(lbuf[2 * i + 1]);
      keep = (s <= rmf[(pc >> 12) & 63] + MARGIN);   // == proven pass-2 criterion
    }
    unsigned long long m = __ballot(keep);
    unsigned wb = 0;
    if ((tid & 63) == 0 && m) wb = atomicAdd(&ccnt, (unsigned)__popcll(m));
    wb = __shfl(wb, 0);
    if (keep) {
      unsigned off = (unsigned)__popcll(m & ((1ull << (tid & 63)) - 1ull));
      unsigned g = wb + off;
      if (g < CBUF_N) cbuf[g] = pc;
      else { unsigned gg = atomicAdd(cnt2, 1u); if (gg < CAP) cand[gg] = pc; }
    }
  }

  // ---- In-block exact verify (fmaf chain bit-identical to verify_k) ----
  __syncthreads();
  unsigned nv = ccnt; if (nv > CBUF_N) nv = CBUF_N;
  for (unsigned i = tid; i < nv; i += 256) {
    unsigned pc = cbuf[i];
    unsigned row = pc >> 12, code = pc & 4095u;
    const float* x = z + (size_t)(row >> 12) * CHW + (row & (HW - 1));
    const float* e = cb + (size_t)code * D_DIM;
    float acc = 0.0f;
#pragma unroll 8
    for (int c = 0; c < D_DIM; ++c) acc = fmaf(x[(size_t)c * HW], e[c], acc);
    float d = (rn_s[row & 63] + en[code]) - 2.0f * acc;   // reference rounding order
    unsigned long long k64 = ((unsigned long long)__float_as_uint(d) << 32) | code;
    atomicMin(&key[row], k64);
  }
}

// Exact re-verify for SPILLS only (normally zero entries). Bit-identical chain.
__global__ void verify_k(const float* __restrict__ z, const float* __restrict__ cb,
                         const float* __restrict__ rn, const float* __restrict__ en,
                         const unsigned int* __restrict__ cand,
                         const unsigned int* __restrict__ cnt,
                         unsigned long long* __restrict__ key) {
  unsigned total = *cnt; if (total > CAP) total = CAP;
  for (unsigned i = blockIdx.x * 256 + threadIdx.x; i < total; i += gridDim.x * 256) {
    unsigned pc = cand[i];
    unsigned row = pc >> 12, code = pc & 4095u;
    const float* x = z + (size_t)(row >> 12) * CHW + (row & (HW - 1));
    const float* e = cb + (size_t)code * D_DIM;
    float acc = 0.0f;
#pragma unroll 8
    for (int c = 0; c < D_DIM; ++c) acc = fmaf(x[(size_t)c * HW], e[c], acc);
    float d = (rn[row] + en[code]) - 2.0f * acc;   // reference rounding order
    unsigned long long k64 = ((unsigned long long)__float_as_uint(d) << 32) | code;
    atomicMin(&key[row], k64);
  }
}

// ---------- fp32 argmin (small-ws fallback AND guarded backstop) ----------
// guard != nullptr: early-exit unless the spill counter overflowed CAP
// (i.e., candidates may have been dropped) -> recompute everything exactly.
#define BM 128
#define BN 128
#define BK 32
#define KQ 1024
#define ES_S 36
__global__ __launch_bounds__(256, 3) void argmin_fb(
    const float* __restrict__ z, const float* __restrict__ cb,
    const float* __restrict__ rn, const float* __restrict__ en,
    unsigned long long* __restrict__ key, const unsigned int* __restrict__ guard) {
  if (guard && *guard <= CAP) return;
  __shared__ union {
    struct { float Xs[BK * BM]; float Es[BN * ES_S]; } s;
    struct { float rv[BM * 16]; int ri[BM * 16]; } r;
  } sh;
  const int tid = threadIdx.x;
  const int tx = tid & 15, ty = tid >> 4;
  const int row_base = (blockIdx.x >> 2) * BM;
  const int q = blockIdx.x & 3;
  const float* zb = z + (size_t)(row_base >> 12) * CHW + (row_base & (HW - 1));
  float rnv[8];
#pragma unroll
  for (int i = 0; i < 8; ++i) rnv[i] = rn[row_base + ty * 8 + i];
  float bestV[8]; int bestI[8];
#pragma unroll
  for (int i = 0; i < 8; ++i) { bestV[i] = 3.4e38f; bestI[i] = 0; }
  for (int t0 = q * KQ; t0 < q * KQ + KQ; t0 += BN) {
    float acc[8][8];
#pragma unroll
    for (int i = 0; i < 8; ++i)
#pragma unroll
      for (int j = 0; j < 8; ++j) acc[i][j] = 0.0f;
    for (int kb = 0; kb < D_DIM; kb += BK) {
      __syncthreads();
#pragma unroll
      for (int k = 0; k < 4; ++k) {
        int l4 = tid + k * 256, cl = l4 >> 5, ro = (l4 & 31) << 2;
        *(float4*)&sh.s.Xs[cl * BM + ro] = *(const float4*)(zb + (size_t)(kb + cl) * HW + ro);
      }
#pragma unroll
      for (int k = 0; k < 4; ++k) {
        int l4 = tid + k * 256, kl = l4 >> 3, cq = (l4 & 7) << 2;
        *(float4*)&sh.s.Es[kl * ES_S + cq] =
            *(const float4*)(cb + (size_t)(t0 + kl) * D_DIM + kb + cq);
      }
      __syncthreads();
#pragma unroll
      for (int c4 = 0; c4 < BK / 4; ++c4) {
        float4 ef[8];
#pragma unroll
        for (int j = 0; j < 8; ++j)
          ef[j] = *(const float4*)&sh.s.Es[(tx + 16 * j) * ES_S + c4 * 4];
#pragma unroll
        for (int cc = 0; cc < 4; ++cc) {
          int c = c4 * 4 + cc;
          float4 xa = *(const float4*)&sh.s.Xs[c * BM + ty * 8];
          float4 xb = *(const float4*)&sh.s.Xs[c * BM + ty * 8 + 4];
          float xv[8] = {xa.x, xa.y, xa.z, xa.w, xb.x, xb.y, xb.z, xb.w};
          float evv[8] = {((const float*)&ef[0])[cc], ((const float*)&ef[1])[cc],
                          ((const float*)&ef[2])[cc], ((const float*)&ef[3])[cc],
                          ((const float*)&ef[4])[cc], ((const float*)&ef[5])[cc],
                          ((const float*)&ef[6])[cc], ((const float*)&ef[7])[cc]};
#pragma unroll
          for (int i = 0; i < 8; ++i)
#pragma unroll
            for (int j = 0; j < 8; ++j) acc[i][j] = fmaf(xv[i], evv[j], acc[i][j]);
        }
      }
    }
#pragma unroll
    for (int j = 0; j < 8; ++j) {
      int code = t0 + tx + 16 * j;
      float ev = en[code];
#pragma unroll
      for (int i = 0; i < 8; ++i) {
        float d = (rnv[i] + ev) - 2.0f * acc[i][j];
        if (d < bestV[i]) { bestV[i] = d; bestI[i] = code; }
      }
    }
  }
  __syncthreads();
#pragma unroll
  for (int i = 0; i < 8; ++i) {
    sh.r.rv[(ty * 8 + i) * 16 + tx] = bestV[i];
    sh.r.ri[(ty * 8 + i) * 16 + tx] = bestI[i];
  }
  __syncthreads();
  if (tid < BM) {
    float bv = sh.r.rv[tid * 16]; int bi = sh.r.ri[tid * 16];
    for (int t = 1; t < 16; ++t) {
      float v = sh.r.rv[tid * 16 + t]; int ii = sh.r.ri[tid * 16 + t];
      if (v < bv || (v == bv && ii < bi)) { bv = v; bi = ii; }
    }
    unsigned long long k64 = ((unsigned long long)__float_as_uint(bv) << 32) | (unsigned)bi;
    atomicMin(&key[row_base + tid], k64);
  }
}
// ---------- end fallback ----------

// quant + folded scatter: c0==0 thread also writes idx, enc one-hot, counts.
__global__ void quant2_k(const float* __restrict__ z, const float* __restrict__ cb,
                         const unsigned long long* __restrict__ key,
                         unsigned int* __restrict__ counts, float* __restrict__ out,
                         double* __restrict__ losssum) {
  __shared__ double red[256];
  int bh = blockIdx.x, b = bh >> 6, h = bh & 63;
  int tid = threadIdx.x, w = tid & 63, c0 = tid >> 6;
  int n = (b << 12) + (h << 6) + w;
  int iv = (int)(unsigned int)(key[n] & 0xffffffffULL);
  if (c0 == 0) {
    out[OFF_IDX + n] = (float)iv;
    out[OFF_ENC + (size_t)n * K_CODES + iv] = 1.0f;
    atomicAdd(&counts[iv], 1u);
  }
  const float* cbr = cb + (size_t)iv * D_DIM;
  size_t zoff = (size_t)b * CHW + (size_t)(h << 6) + w;
  double s = 0.0;
  for (int c = c0; c < D_DIM; c += 4) {
    float zv = z[zoff + (size_t)c * HW];
    float qv = cbr[c];
    float diff = qv - zv;
    out[OFF_QUANT + zoff + (size_t)c * HW] = zv + diff;   // STE forward rounding
    double dd = (double)qv - (double)zv;
    s += dd * dd;
  }
  red[tid] = s;
  __syncthreads();
  for (int st = 128; st > 0; st >>= 1) {
    if (tid < st) red[tid] += red[tid + st];
    __syncthreads();
  }
  if (tid == 0) atomicAdd(losssum, red[0]);
}

__global__ void final_k(const unsigned int* __restrict__ counts,
                        const double* __restrict__ losssum, float* __restrict__ out) {
  __shared__ double red[256];
  int tid = threadIdx.x;
  double s = 0.0;
  for (int k = tid; k < K_CODES; k += 256) {
    double p = (double)counts[k] / 32768.0;
    s += p * log(p + 1e-10);
  }
  red[tid] = s;
  __syncthreads();
  for (int st = 128; st > 0; st >>= 1) {
    if (tid < st) red[tid] += red[tid + st];
    __syncthreads();
  }
  if (tid == 0) {
    out[OFF_PERP] = (float)exp(-red[0]);
    out[OFF_LOSS] = (float)(1.25 * losssum[0] / 8388608.0);
  }
}

extern "C" void kernel_launch(void* const* d_in, const int* in_sizes, int n_in,
                              void* d_out, int out_size, void* d_ws, size_t ws_size,
                              hipStream_t stream) {
  (void)in_sizes; (void)n_in; (void)out_size;
  const float* z = (const float*)d_in[0];
  const float* cb = (const float*)d_in[1];
  float* out = (float*)d_out;
  float* ws = (float*)d_ws;

  float* rn = ws + WS_RN;
  float* en = ws + WS_EN;
  unsigned long long* key = (unsigned long long*)(ws + WS_KEY);
  unsigned int* counts = (unsigned int*)(ws + WS_CNT);
  double* losssum = (double*)(ws + WS_LOSS);

  hipMemsetAsync(ws + WS_KEY, 0xFF, (size_t)N_ROWS * sizeof(unsigned long long), stream);

  enorm_k<<<K_CODES / 256, 256, 0, stream>>>(cb, en);

  if (ws_size >= WS_NEED_BYTES) {
    unsigned int* cnt2 = (unsigned int*)(ws + WS_CNT2);
    unsigned int* cand = (unsigned int*)(ws + WS_CAND);
    unsigned short* cbf = (unsigned short*)(ws + WS_CBF);
    // zero counts(4096) + loss(2) + counters + pad
    hipMemsetAsync(ws + WS_CNT, 0, (WS_THR - WS_CNT) * sizeof(float), stream);
    cbbf_k<<<(K_CODES * D_DIM / 4) / 256, 256, 0, stream>>>(cb, cbf);
    // SINGLE MFMA pass: fused rownorm + folded enc-zeroing + online emission
    // + in-block re-cut + IN-BLOCK exact verify (writes key[] directly).
    pass5v_k<<<N_ROWS / 64, 256, 0, stream>>>(z, cb, cbf, en, rn,
                                              out + OFF_ENC, key, cand, cnt2);
    // Spill-only verify (normally zero entries -> near-free dispatch).
    verify_k<<<256, 256, 0, stream>>>(z, cb, rn, en, cand, cnt2, key);
    // Guarded backstop: full exact recompute ONLY if the spill list overflowed.
    argmin_fb<<<(N_ROWS / BM) * 4, 256, 0, stream>>>(z, cb, rn, en, key, cnt2);
  } else {
    hipMemsetAsync(out + OFF_ENC, 0, (size_t)N_ROWS * K_CODES * sizeof(float), stream);
    rownorm_k<<<N_ROWS / 256, 256, 0, stream>>>(z, rn);
    hipMemsetAsync(ws + WS_CNT, 0, K_CODES * sizeof(unsigned int) + 2 * sizeof(double), stream);
    argmin_fb<<<(N_ROWS / BM) * 4, 256, 0, stream>>>(z, cb, rn, en, key, nullptr);
  }

  quant2_k<<<512, 256, 0, stream>>>(z, cb, key, counts, out, losssum);
  final_k<<<1, 256, 0, stream>>>(counts, losssum, out);
}